// Round 6
// baseline (382.360 us; speedup 1.0000x reference)
//
#include <hip/hip_runtime.h>

typedef float floatx4 __attribute__((ext_vector_type(4)));
typedef short shortx8 __attribute__((ext_vector_type(8)));

#define E_DIM 1024
#define F_DIM 4096
#define BATCH 4
#define SEQ 1024
#define NH 16
#define HD 64
#define MROWS (BATCH*SEQ)   // 4096
#define QKV_N (3*E_DIM)     // 3072

typedef const __attribute__((address_space(1))) unsigned int* gas_ptr;
typedef __attribute__((address_space(3))) unsigned int* las_ptr;

__device__ __forceinline__ unsigned short f2bf(float f) {
    union { float f; unsigned u; } un; un.f = f;
    unsigned u = un.u;
    u += 0x7fffu + ((u >> 16) & 1u);   // RNE
    return (unsigned short)(u >> 16);
}

// XCD-aware tile remap: blocks dispatch round-robin to XCDs (i%8), so give
// XCD k the m-tiles [k*mt/8, (k+1)*mt/8) across all n -> per-XCD L2 holds its
// A share; A re-reads become L2 hits. Requires gridDim.y % 8 == 0.
__device__ __forceinline__ void xcd_remap(int& m_idx, int& n_idx) {
    int nt = gridDim.x;
    int lin = blockIdx.y * nt + blockIdx.x;
    int xcd = lin & 7, loc = lin >> 3;
    int q = loc / nt;
    m_idx = xcd * (gridDim.y >> 3) + q;
    n_idx = loc - q * nt;
}

// ---------------- fp32 -> bf16 convert (weights) ----------------
__global__ void f2b_kernel(const float* __restrict__ in, unsigned short* __restrict__ out, int n) {
    int i = blockIdx.x * 256 + threadIdx.x;
    if (i < n) out[i] = f2bf(in[i]);
}

// ---------------- LayerNorm (row=1024), fp32 in, bf16 out ----------------
__global__ __launch_bounds__(256) void ln_kernel(const float* __restrict__ x,
                                                 const float* __restrict__ w,
                                                 const float* __restrict__ b,
                                                 unsigned short* __restrict__ out) {
    int row = blockIdx.x;
    const float* xr = x + (size_t)row * E_DIM;
    float v[4];
    float s = 0.f, ss = 0.f;
    for (int i = 0; i < 4; ++i) {
        v[i] = xr[threadIdx.x + i * 256];
        s += v[i]; ss += v[i] * v[i];
    }
    for (int m = 32; m; m >>= 1) { s += __shfl_xor(s, m); ss += __shfl_xor(ss, m); }
    __shared__ float red[8];
    int wave = threadIdx.x >> 6;
    if ((threadIdx.x & 63) == 0) { red[wave] = s; red[wave + 4] = ss; }
    __syncthreads();
    s = red[0] + red[1] + red[2] + red[3];
    ss = red[4] + red[5] + red[6] + red[7];
    float mu = s * (1.0f / E_DIM);
    float var = ss * (1.0f / E_DIM) - mu * mu;
    float rs = rsqrtf(var + 1e-5f);
    for (int i = 0; i < 4; ++i) {
        int c = threadIdx.x + i * 256;
        out[(size_t)row * E_DIM + c] = f2bf((v[i] - mu) * rs * w[c] + b[c]);
    }
}

// ---------------- GEMM 128x128 (m97 structure) — for N>=3072 GEMMs ----------------
#define TM 128
#define TN 128
#define BK 64

template<int EPI>
__global__ __launch_bounds__(256) void gemm_bt(
        const unsigned short* __restrict__ A, const unsigned short* __restrict__ Bw,
        const float* __restrict__ bias, const float* __restrict__ resid,
        float* __restrict__ Cf, unsigned short* __restrict__ Cb,
        int M, int N, int K) {
    __shared__ unsigned short sA[TM * BK];
    __shared__ unsigned short sB[TN * BK];
    int tid = threadIdx.x;
    int wave = tid >> 6, lane = tid & 63;
    int m_idx, n_idx;
    xcd_remap(m_idx, n_idx);
    int n0 = n_idx * TN, m0 = m_idx * TM;
    int wm = (wave & 1) * 64, wn = (wave >> 1) * 64;
    int l15 = lane & 15, quad = lane >> 4;

    int srow = wave * 32 + (lane >> 3);
    int scg  = (lane & 7) ^ (srow & 7);
    const unsigned short* Ag = A  + (size_t)(m0 + srow) * K + scg * 8;
    const unsigned short* Bg = Bw + (size_t)(n0 + srow) * K + scg * 8;

    floatx4 acc[4][4];
#pragma unroll
    for (int i = 0; i < 4; ++i)
#pragma unroll
        for (int j = 0; j < 4; ++j) acc[i][j] = (floatx4)0.f;

    for (int k0 = 0; k0 < K; k0 += BK) {
        __syncthreads();
#pragma unroll
        for (int p = 0; p < 4; ++p) {
            __builtin_amdgcn_global_load_lds((gas_ptr)(Ag + k0 + p * 8 * K),
                (las_ptr)&sA[(wave * 32 + p * 8) * BK], 16, 0, 0);
            __builtin_amdgcn_global_load_lds((gas_ptr)(Bg + k0 + p * 8 * K),
                (las_ptr)&sB[(wave * 32 + p * 8) * BK], 16, 0, 0);
        }
        __syncthreads();
#pragma unroll
        for (int kk8 = 0; kk8 < 8; kk8 += 4) {
            shortx8 af[4], bfr[4];
#pragma unroll
            for (int i = 0; i < 4; ++i) {
                int R = wm + i * 16 + l15;
                int sc = (quad + kk8) ^ (R & 7);
                af[i] = *(const shortx8*)&sA[(R * 8 + sc) * 8];
            }
#pragma unroll
            for (int j = 0; j < 4; ++j) {
                int R = wn + j * 16 + l15;
                int sc = (quad + kk8) ^ (R & 7);
                bfr[j] = *(const shortx8*)&sB[(R * 8 + sc) * 8];
            }
#pragma unroll
            for (int i = 0; i < 4; ++i)
#pragma unroll
                for (int j = 0; j < 4; ++j)
                    acc[i][j] = __builtin_amdgcn_mfma_f32_16x16x32_bf16(af[i], bfr[j], acc[i][j], 0, 0, 0);
        }
    }

#pragma unroll
    for (int i = 0; i < 4; ++i) {
        int row = m0 + wm + i * 16 + quad * 4;
#pragma unroll
        for (int j = 0; j < 4; ++j) {
            int col = n0 + wn + j * 16 + l15;
            float bs = bias[col];
#pragma unroll
            for (int r = 0; r < 4; ++r) {
                float v = acc[i][j][r] + bs;
                int rr = row + r;
                if (EPI & 1) v = 0.5f * v * (1.0f + erff(v * 0.70710678f));
                if (EPI & 2) v += resid[(size_t)rr * N + col];
                if (EPI & 4) Cf[(size_t)rr * N + col] = v;
                if (EPI & 8) Cb[(size_t)rr * N + col] = f2bf(v);
            }
        }
    }
}

// ---------------- GEMM 128x64 — for N=1024 GEMMs (2 blocks/CU) ----------------
template<int EPI>
__global__ __launch_bounds__(256) void gemm_n64(
        const unsigned short* __restrict__ A, const unsigned short* __restrict__ Bw,
        const float* __restrict__ bias, const float* __restrict__ resid,
        float* __restrict__ Cf, unsigned short* __restrict__ Cb,
        int M, int N, int K) {
    __shared__ unsigned short sA[TM * BK];
    __shared__ unsigned short sB[64 * BK];
    int tid = threadIdx.x;
    int wave = tid >> 6, lane = tid & 63;
    int m_idx, n_idx;
    xcd_remap(m_idx, n_idx);
    int n0 = n_idx * 64, m0 = m_idx * TM;
    int wm = (wave & 1) * 64, wn = (wave >> 1) * 32;
    int l15 = lane & 15, quad = lane >> 4;

    int srow = wave * 32 + (lane >> 3);
    int scg  = (lane & 7) ^ (srow & 7);
    const unsigned short* Ag = A + (size_t)(m0 + srow) * K + scg * 8;
    int srB  = wave * 16 + (lane >> 3);
    int scgB = (lane & 7) ^ (srB & 7);
    const unsigned short* Bg = Bw + (size_t)(n0 + srB) * K + scgB * 8;

    floatx4 acc[4][2];
#pragma unroll
    for (int i = 0; i < 4; ++i)
#pragma unroll
        for (int j = 0; j < 2; ++j) acc[i][j] = (floatx4)0.f;

    for (int k0 = 0; k0 < K; k0 += BK) {
        __syncthreads();
#pragma unroll
        for (int p = 0; p < 4; ++p)
            __builtin_amdgcn_global_load_lds((gas_ptr)(Ag + k0 + p * 8 * K),
                (las_ptr)&sA[(wave * 32 + p * 8) * BK], 16, 0, 0);
#pragma unroll
        for (int p = 0; p < 2; ++p)
            __builtin_amdgcn_global_load_lds((gas_ptr)(Bg + k0 + p * 8 * K),
                (las_ptr)&sB[(wave * 16 + p * 8) * BK], 16, 0, 0);
        __syncthreads();
#pragma unroll
        for (int kk8 = 0; kk8 < 8; kk8 += 4) {
            shortx8 af[4], bfr[2];
#pragma unroll
            for (int i = 0; i < 4; ++i) {
                int R = wm + i * 16 + l15;
                int sc = (quad + kk8) ^ (R & 7);
                af[i] = *(const shortx8*)&sA[(R * 8 + sc) * 8];
            }
#pragma unroll
            for (int j = 0; j < 2; ++j) {
                int R = wn + j * 16 + l15;
                int sc = (quad + kk8) ^ (R & 7);
                bfr[j] = *(const shortx8*)&sB[(R * 8 + sc) * 8];
            }
#pragma unroll
            for (int i = 0; i < 4; ++i)
#pragma unroll
                for (int j = 0; j < 2; ++j)
                    acc[i][j] = __builtin_amdgcn_mfma_f32_16x16x32_bf16(af[i], bfr[j], acc[i][j], 0, 0, 0);
        }
    }

#pragma unroll
    for (int i = 0; i < 4; ++i) {
        int row = m0 + wm + i * 16 + quad * 4;
#pragma unroll
        for (int j = 0; j < 2; ++j) {
            int col = n0 + wn + j * 16 + l15;
            float bs = bias[col];
#pragma unroll
            for (int r = 0; r < 4; ++r) {
                float v = acc[i][j][r] + bs;
                int rr = row + r;
                if (EPI & 1) v = 0.5f * v * (1.0f + erff(v * 0.70710678f));
                if (EPI & 2) v += resid[(size_t)rr * N + col];
                if (EPI & 4) Cf[(size_t)rr * N + col] = v;
                if (EPI & 8) Cb[(size_t)rr * N + col] = f2bf(v);
            }
        }
    }
}

// ---------------- V transpose: qkv[.,2048+h*64+d] -> vT[bh][d][t] ----------------
__global__ __launch_bounds__(256) void vtrans_kernel(const unsigned short* __restrict__ qkv,
                                                     unsigned short* __restrict__ vT) {
    __shared__ unsigned short tile[64 * 72];
    int tid = threadIdx.x;
    int bh = blockIdx.y, b = bh >> 4, h = bh & 15;
    int t0 = blockIdx.x * 64;
    const unsigned short* vsrc = qkv + (size_t)b * SEQ * QKV_N + 2 * E_DIM + h * HD;
#pragma unroll
    for (int p = 0; p < 2; ++p) {
        int idx = p * 256 + tid;
        int row = idx >> 3, col = (idx & 7) * 8;
        *(shortx8*)&tile[row * 72 + col] =
            *(const shortx8*)&vsrc[(size_t)(t0 + row) * QKV_N + col];
    }
    __syncthreads();
    int d = tid >> 2, tch = (tid & 3) * 16;
    unsigned short* dst = vT + (size_t)bh * HD * SEQ + (size_t)d * SEQ + t0 + tch;
    shortx8 a0, a1;
#pragma unroll
    for (int j = 0; j < 8; ++j) a0[j] = (short)tile[(tch + j) * 72 + d];
#pragma unroll
    for (int j = 0; j < 8; ++j) a1[j] = (short)tile[(tch + 8 + j) * 72 + d];
    *(shortx8*)&dst[0] = a0;
    *(shortx8*)&dst[8] = a1;
}

// ---------------- Flash attention: 64-key tiles, paired q-tiles, swizzled LDS ----------------
__global__ __launch_bounds__(256) void attn_kernel(
        const unsigned short* __restrict__ qkv, const unsigned short* __restrict__ vT,
        unsigned short* __restrict__ out) {
    __shared__ unsigned short kt[64 * 64];
    __shared__ unsigned short vt[64 * 64];
    __shared__ unsigned short ps[4][16 * 64];
    int tid = threadIdx.x;
    int wave = tid >> 6, lane = tid & 63, l15 = lane & 15, quad = lane >> 4;
    int bh = blockIdx.y, b = bh >> 4, h = bh & 15;
    const unsigned short* qbase = qkv + (size_t)b * SEQ * QKV_N + h * HD;
    const unsigned short* kbase = qbase + E_DIM;
    const unsigned short* vtb = vT + (size_t)bh * HD * SEQ;

    int srl = lane >> 3;
    int scg = (lane & 7) ^ srl;

    const float scale = 0.125f * 1.44269504f;

    for (int pass = 0; pass < 2; ++pass) {
        int qt = (pass == 0) ? blockIdx.x : (15 - blockIdx.x);
        int q0 = qt * 64;
        int qrow = q0 + wave * 16;

        shortx8 qa0 = *(const shortx8*)&qbase[(size_t)(qrow + l15) * QKV_N + quad * 8];
        shortx8 qa1 = *(const shortx8*)&qbase[(size_t)(qrow + l15) * QKV_N + 32 + quad * 8];

        floatx4 o[4];
        for (int d = 0; d < 4; ++d) o[d] = (floatx4)0.f;
        float mrun[4], lrun[4];
        for (int r = 0; r < 4; ++r) { mrun[r] = -1e30f; lrun[r] = 0.f; }

        int ntile = qt + 1;
        for (int t = 0; t < ntile; ++t) {
            int s0 = t * 64;
            __syncthreads();
#pragma unroll
            for (int p = 0; p < 2; ++p) {
                int rbase = p * 32 + wave * 8;
                __builtin_amdgcn_global_load_lds(
                    (gas_ptr)&kbase[(size_t)(s0 + rbase + srl) * QKV_N + scg * 8],
                    (las_ptr)&kt[rbase * 64], 16, 0, 0);
                __builtin_amdgcn_global_load_lds(
                    (gas_ptr)&vtb[(size_t)(rbase + srl) * SEQ + s0 + scg * 8],
                    (las_ptr)&vt[rbase * 64], 16, 0, 0);
            }
            __syncthreads();

            floatx4 sfr[4];
#pragma unroll
            for (int ct = 0; ct < 4; ++ct) {
                int R = ct * 16 + l15;
                int sc0 = quad ^ (R & 7), sc1 = (4 + quad) ^ (R & 7);
                shortx8 kb0 = *(const shortx8*)&kt[(R * 8 + sc0) * 8];
                shortx8 kb1 = *(const shortx8*)&kt[(R * 8 + sc1) * 8];
                floatx4 s4 = (floatx4)0.f;
                s4 = __builtin_amdgcn_mfma_f32_16x16x32_bf16(qa0, kb0, s4, 0, 0, 0);
                s4 = __builtin_amdgcn_mfma_f32_16x16x32_bf16(qa1, kb1, s4, 0, 0, 0);
                sfr[ct] = s4;
            }

            bool masked = (t == ntile - 1);
#pragma unroll
            for (int r = 0; r < 4; ++r) {
                int qg = qrow + quad * 4 + r;
                float sv[4];
                float mx = mrun[r];
#pragma unroll
                for (int ct = 0; ct < 4; ++ct) {
                    float v = sfr[ct][r] * scale;
                    if (masked && (s0 + ct * 16 + l15 > qg)) v = -1e30f;
                    sv[ct] = v;
                    mx = fmaxf(mx, v);
                }
                for (int mm = 8; mm; mm >>= 1) mx = fmaxf(mx, __shfl_xor(mx, mm));
                float alpha = exp2f(mrun[r] - mx);
                mrun[r] = mx;
                float sum = 0.f;
                float pv[4];
#pragma unroll
                for (int ct = 0; ct < 4; ++ct) { pv[ct] = exp2f(sv[ct] - mx); sum += pv[ct]; }
                for (int mm = 8; mm; mm >>= 1) sum += __shfl_xor(sum, mm);
                lrun[r] = lrun[r] * alpha + sum;
#pragma unroll
                for (int d = 0; d < 4; ++d) o[d][r] *= alpha;
                int row = quad * 4 + r;
#pragma unroll
                for (int ct = 0; ct < 4; ++ct) {
                    int g = ct * 2 + (l15 >> 3);
                    int sc = g ^ (row & 7);
                    ps[wave][row * 64 + sc * 8 + (l15 & 7)] = f2bf(pv[ct]);
                }
            }
            shortx8 pa0, pa1;
            {
                int sc0 = quad ^ (l15 & 7), sc1 = (4 + quad) ^ (l15 & 7);
                pa0 = *(const shortx8*)&ps[wave][(l15 * 8 + sc0) * 8];
                pa1 = *(const shortx8*)&ps[wave][(l15 * 8 + sc1) * 8];
            }
#pragma unroll
            for (int d = 0; d < 4; ++d) {
                int R = d * 16 + l15;
                int sc0 = quad ^ (R & 7), sc1 = (4 + quad) ^ (R & 7);
                shortx8 vb0 = *(const shortx8*)&vt[(R * 8 + sc0) * 8];
                shortx8 vb1 = *(const shortx8*)&vt[(R * 8 + sc1) * 8];
                o[d] = __builtin_amdgcn_mfma_f32_16x16x32_bf16(pa0, vb0, o[d], 0, 0, 0);
                o[d] = __builtin_amdgcn_mfma_f32_16x16x32_bf16(pa1, vb1, o[d], 0, 0, 0);
            }
        }

#pragma unroll
        for (int r = 0; r < 4; ++r) {
            float inv = 1.0f / lrun[r];
            int m = (b << 10) + qrow + quad * 4 + r;
#pragma unroll
            for (int d = 0; d < 4; ++d)
                out[(size_t)m * E_DIM + h * HD + d * 16 + l15] = f2bf(o[d][r] * inv);
        }
    }
}

// ---------------- launch ----------------
extern "C" void kernel_launch(void* const* d_in, const int* in_sizes, int n_in,
                              void* d_out, int out_size, void* d_ws, size_t ws_size,
                              hipStream_t stream) {
    const float* x     = (const float*)d_in[0];
    const float* ln1_w = (const float*)d_in[1];
    const float* ln1_b = (const float*)d_in[2];
    const float* ln2_w = (const float*)d_in[3];
    const float* ln2_b = (const float*)d_in[4];
    const float* qkv_w = (const float*)d_in[5];
    const float* qkv_b = (const float*)d_in[6];
    const float* out_w = (const float*)d_in[7];
    const float* out_b = (const float*)d_in[8];
    const float* fc1_w = (const float*)d_in[9];
    const float* fc1_b = (const float*)d_in[10];
    const float* fc2_w = (const float*)d_in[11];
    const float* fc2_b = (const float*)d_in[12];

    char* ws = (char*)d_ws;
    size_t off = 0;
    auto alloc = [&](size_t bytes) { char* p = ws + off; off += bytes; return p; };
    unsigned short* wq   = (unsigned short*)alloc((size_t)3 * E_DIM * E_DIM * 2);
    unsigned short* wo   = (unsigned short*)alloc((size_t)E_DIM * E_DIM * 2);
    unsigned short* w1   = (unsigned short*)alloc((size_t)F_DIM * E_DIM * 2);
    unsigned short* w2   = (unsigned short*)alloc((size_t)E_DIM * F_DIM * 2);
    unsigned short* h1   = (unsigned short*)alloc((size_t)MROWS * E_DIM * 2);
    unsigned short* qkvb = (unsigned short*)alloc((size_t)MROWS * QKV_N * 2);
    unsigned short* vT   = (unsigned short*)alloc((size_t)BATCH * NH * HD * SEQ * 2);
    unsigned short* attn = (unsigned short*)alloc((size_t)MROWS * E_DIM * 2);
    float*          x1   = (float*)alloc((size_t)MROWS * E_DIM * 4);
    unsigned short* h2   = (unsigned short*)alloc((size_t)MROWS * E_DIM * 2);
    unsigned short* g    = (unsigned short*)alloc((size_t)MROWS * F_DIM * 2);

    {
        int n;
        n = 3 * E_DIM * E_DIM; f2b_kernel<<<(n + 255) / 256, 256, 0, stream>>>(qkv_w, wq, n);
        n = E_DIM * E_DIM;     f2b_kernel<<<(n + 255) / 256, 256, 0, stream>>>(out_w, wo, n);
        n = F_DIM * E_DIM;     f2b_kernel<<<(n + 255) / 256, 256, 0, stream>>>(fc1_w, w1, n);
        n = E_DIM * F_DIM;     f2b_kernel<<<(n + 255) / 256, 256, 0, stream>>>(fc2_w, w2, n);
    }

    ln_kernel<<<MROWS, 256, 0, stream>>>(x, ln1_w, ln1_b, h1);
    gemm_bt<8><<<dim3(QKV_N / TN, MROWS / TM), 256, 0, stream>>>(
        h1, wq, qkv_b, nullptr, nullptr, qkvb, MROWS, QKV_N, E_DIM);
    vtrans_kernel<<<dim3(SEQ / 64, BATCH * NH), 256, 0, stream>>>(qkvb, vT);
    attn_kernel<<<dim3(8, BATCH * NH), 256, 0, stream>>>(qkvb, vT, attn);
    // out proj + residual(x) -> x1 fp32   (N=1024: 128x64 tiles, 512 blocks)
    gemm_n64<2 | 4><<<dim3(E_DIM / 64, MROWS / TM), 256, 0, stream>>>(
        attn, wo, out_b, x, x1, nullptr, MROWS, E_DIM, E_DIM);
    ln_kernel<<<MROWS, 256, 0, stream>>>(x1, ln2_w, ln2_b, h2);
    gemm_bt<1 | 8><<<dim3(F_DIM / TN, MROWS / TM), 256, 0, stream>>>(
        h2, w1, fc1_b, nullptr, nullptr, g, MROWS, F_DIM, E_DIM);
    // FC2 + residual(x1) -> d_out fp32   (N=1024: 128x64 tiles, 512 blocks)
    gemm_n64<2 | 4><<<dim3(E_DIM / 64, MROWS / TM), 256, 0, stream>>>(
        g, w2, fc2_b, x1, (float*)d_out, nullptr, MROWS, E_DIM, F_DIM);
}

// Round 7
// 368.737 us; speedup vs baseline: 1.0369x; 1.0369x over previous
//
#include <hip/hip_runtime.h>

typedef float floatx4 __attribute__((ext_vector_type(4)));
typedef short shortx8 __attribute__((ext_vector_type(8)));

#define E_DIM 1024
#define F_DIM 4096
#define BATCH 4
#define SEQ 1024
#define NH 16
#define HD 64
#define MROWS (BATCH*SEQ)   // 4096
#define QKV_N (3*E_DIM)     // 3072

typedef const __attribute__((address_space(1))) unsigned int* gas_ptr;
typedef __attribute__((address_space(3))) unsigned int* las_ptr;

__device__ __forceinline__ unsigned short f2bf(float f) {
    union { float f; unsigned u; } un; un.f = f;
    unsigned u = un.u;
    u += 0x7fffu + ((u >> 16) & 1u);   // RNE
    return (unsigned short)(u >> 16);
}

// tanh-form GELU via sigmoid: gelu(x) ~= x * sigmoid(1.59577*(x + 0.044715 x^3))*... 
// exactly: u = sqrt(2/pi)*(x+0.044715x^3); gelu = x*sigmoid(2u) = x/(1+exp2(-2u*log2e))
__device__ __forceinline__ float gelu_fast(float v) {
    float u = 0.7978845608f * (v + 0.044715f * v * v * v);
    return v / (1.0f + __builtin_exp2f(-2.885390082f * u));  // 2*log2(e)*u
}

// XCD-aware tile remap, m-fastest within XCD: blocks dispatch round-robin to
// XCDs (i%8); XCD k owns m-tiles [k*mt/8,(k+1)*mt/8). m varies fastest so the
// concurrent blocks span all owned m-tiles but few n-tiles -> working set
// (A-share + B-chunk) fits the 4 MiB per-XCD L2. Requires gridDim.y % 8 == 0.
__device__ __forceinline__ void xcd_remap(int& m_idx, int& n_idx) {
    int nt = gridDim.x;
    int mt_x = gridDim.y >> 3;
    int lin = blockIdx.y * nt + blockIdx.x;
    int xcd = lin & 7, loc = lin >> 3;
    int n = loc / mt_x;
    int m_local = loc - n * mt_x;
    m_idx = xcd * mt_x + m_local;
    n_idx = n;
}

// ---------------- fp32 -> bf16 convert (weights) ----------------
__global__ void f2b_kernel(const float* __restrict__ in, unsigned short* __restrict__ out, int n) {
    int i = blockIdx.x * 256 + threadIdx.x;
    if (i < n) out[i] = f2bf(in[i]);
}

// ---------------- LayerNorm (row=1024), fp32 in, bf16 out ----------------
__global__ __launch_bounds__(256) void ln_kernel(const float* __restrict__ x,
                                                 const float* __restrict__ w,
                                                 const float* __restrict__ b,
                                                 unsigned short* __restrict__ out) {
    int row = blockIdx.x;
    const float* xr = x + (size_t)row * E_DIM;
    float v[4];
    float s = 0.f, ss = 0.f;
    for (int i = 0; i < 4; ++i) {
        v[i] = xr[threadIdx.x + i * 256];
        s += v[i]; ss += v[i] * v[i];
    }
    for (int m = 32; m; m >>= 1) { s += __shfl_xor(s, m); ss += __shfl_xor(ss, m); }
    __shared__ float red[8];
    int wave = threadIdx.x >> 6;
    if ((threadIdx.x & 63) == 0) { red[wave] = s; red[wave + 4] = ss; }
    __syncthreads();
    s = red[0] + red[1] + red[2] + red[3];
    ss = red[4] + red[5] + red[6] + red[7];
    float mu = s * (1.0f / E_DIM);
    float var = ss * (1.0f / E_DIM) - mu * mu;
    float rs = rsqrtf(var + 1e-5f);
    for (int i = 0; i < 4; ++i) {
        int c = threadIdx.x + i * 256;
        out[(size_t)row * E_DIM + c] = f2bf((v[i] - mu) * rs * w[c] + b[c]);
    }
}

// ---------------- GEMM 128x128 (m97 structure) — for N>=3072 GEMMs ----------------
#define TM 128
#define TN 128
#define BK 64

template<int EPI>
__global__ __launch_bounds__(256) void gemm_bt(
        const unsigned short* __restrict__ A, const unsigned short* __restrict__ Bw,
        const float* __restrict__ bias, const float* __restrict__ resid,
        float* __restrict__ Cf, unsigned short* __restrict__ Cb,
        int M, int N, int K) {
    __shared__ unsigned short sA[TM * BK];
    __shared__ unsigned short sB[TN * BK];
    int tid = threadIdx.x;
    int wave = tid >> 6, lane = tid & 63;
    int m_idx, n_idx;
    xcd_remap(m_idx, n_idx);
    int n0 = n_idx * TN, m0 = m_idx * TM;
    int wm = (wave & 1) * 64, wn = (wave >> 1) * 64;
    int l15 = lane & 15, quad = lane >> 4;

    int srow = wave * 32 + (lane >> 3);
    int scg  = (lane & 7) ^ (srow & 7);
    const unsigned short* Ag = A  + (size_t)(m0 + srow) * K + scg * 8;
    const unsigned short* Bg = Bw + (size_t)(n0 + srow) * K + scg * 8;

    floatx4 acc[4][4];
#pragma unroll
    for (int i = 0; i < 4; ++i)
#pragma unroll
        for (int j = 0; j < 4; ++j) acc[i][j] = (floatx4)0.f;

    for (int k0 = 0; k0 < K; k0 += BK) {
        __syncthreads();
#pragma unroll
        for (int p = 0; p < 4; ++p) {
            __builtin_amdgcn_global_load_lds((gas_ptr)(Ag + k0 + p * 8 * K),
                (las_ptr)&sA[(wave * 32 + p * 8) * BK], 16, 0, 0);
            __builtin_amdgcn_global_load_lds((gas_ptr)(Bg + k0 + p * 8 * K),
                (las_ptr)&sB[(wave * 32 + p * 8) * BK], 16, 0, 0);
        }
        __syncthreads();
#pragma unroll
        for (int kk8 = 0; kk8 < 8; kk8 += 4) {
            shortx8 af[4], bfr[4];
#pragma unroll
            for (int i = 0; i < 4; ++i) {
                int R = wm + i * 16 + l15;
                int sc = (quad + kk8) ^ (R & 7);
                af[i] = *(const shortx8*)&sA[(R * 8 + sc) * 8];
            }
#pragma unroll
            for (int j = 0; j < 4; ++j) {
                int R = wn + j * 16 + l15;
                int sc = (quad + kk8) ^ (R & 7);
                bfr[j] = *(const shortx8*)&sB[(R * 8 + sc) * 8];
            }
#pragma unroll
            for (int i = 0; i < 4; ++i)
#pragma unroll
                for (int j = 0; j < 4; ++j)
                    acc[i][j] = __builtin_amdgcn_mfma_f32_16x16x32_bf16(af[i], bfr[j], acc[i][j], 0, 0, 0);
        }
    }

#pragma unroll
    for (int i = 0; i < 4; ++i) {
        int row = m0 + wm + i * 16 + quad * 4;
#pragma unroll
        for (int j = 0; j < 4; ++j) {
            int col = n0 + wn + j * 16 + l15;
            float bs = bias[col];
#pragma unroll
            for (int r = 0; r < 4; ++r) {
                float v = acc[i][j][r] + bs;
                int rr = row + r;
                if (EPI & 1) v = gelu_fast(v);
                if (EPI & 2) v += resid[(size_t)rr * N + col];
                if (EPI & 4) Cf[(size_t)rr * N + col] = v;
                if (EPI & 8) Cb[(size_t)rr * N + col] = f2bf(v);
            }
        }
    }
}

// ---------------- GEMM 128x64 — for N=1024 GEMMs (2 blocks/CU) ----------------
template<int EPI>
__global__ __launch_bounds__(256) void gemm_n64(
        const unsigned short* __restrict__ A, const unsigned short* __restrict__ Bw,
        const float* __restrict__ bias, const float* __restrict__ resid,
        float* __restrict__ Cf, unsigned short* __restrict__ Cb,
        int M, int N, int K) {
    __shared__ unsigned short sA[TM * BK];
    __shared__ unsigned short sB[64 * BK];
    int tid = threadIdx.x;
    int wave = tid >> 6, lane = tid & 63;
    int m_idx, n_idx;
    xcd_remap(m_idx, n_idx);
    int n0 = n_idx * 64, m0 = m_idx * TM;
    int wm = (wave & 1) * 64, wn = (wave >> 1) * 32;
    int l15 = lane & 15, quad = lane >> 4;

    int srow = wave * 32 + (lane >> 3);
    int scg  = (lane & 7) ^ (srow & 7);
    const unsigned short* Ag = A + (size_t)(m0 + srow) * K + scg * 8;
    int srB  = wave * 16 + (lane >> 3);
    int scgB = (lane & 7) ^ (srB & 7);
    const unsigned short* Bg = Bw + (size_t)(n0 + srB) * K + scgB * 8;

    floatx4 acc[4][2];
#pragma unroll
    for (int i = 0; i < 4; ++i)
#pragma unroll
        for (int j = 0; j < 2; ++j) acc[i][j] = (floatx4)0.f;

    for (int k0 = 0; k0 < K; k0 += BK) {
        __syncthreads();
#pragma unroll
        for (int p = 0; p < 4; ++p)
            __builtin_amdgcn_global_load_lds((gas_ptr)(Ag + k0 + p * 8 * K),
                (las_ptr)&sA[(wave * 32 + p * 8) * BK], 16, 0, 0);
#pragma unroll
        for (int p = 0; p < 2; ++p)
            __builtin_amdgcn_global_load_lds((gas_ptr)(Bg + k0 + p * 8 * K),
                (las_ptr)&sB[(wave * 16 + p * 8) * BK], 16, 0, 0);
        __syncthreads();
#pragma unroll
        for (int kk8 = 0; kk8 < 8; kk8 += 4) {
            shortx8 af[4], bfr[2];
#pragma unroll
            for (int i = 0; i < 4; ++i) {
                int R = wm + i * 16 + l15;
                int sc = (quad + kk8) ^ (R & 7);
                af[i] = *(const shortx8*)&sA[(R * 8 + sc) * 8];
            }
#pragma unroll
            for (int j = 0; j < 2; ++j) {
                int R = wn + j * 16 + l15;
                int sc = (quad + kk8) ^ (R & 7);
                bfr[j] = *(const shortx8*)&sB[(R * 8 + sc) * 8];
            }
#pragma unroll
            for (int i = 0; i < 4; ++i)
#pragma unroll
                for (int j = 0; j < 2; ++j)
                    acc[i][j] = __builtin_amdgcn_mfma_f32_16x16x32_bf16(af[i], bfr[j], acc[i][j], 0, 0, 0);
        }
    }

#pragma unroll
    for (int i = 0; i < 4; ++i) {
        int row = m0 + wm + i * 16 + quad * 4;
#pragma unroll
        for (int j = 0; j < 2; ++j) {
            int col = n0 + wn + j * 16 + l15;
            float bs = bias[col];
#pragma unroll
            for (int r = 0; r < 4; ++r) {
                float v = acc[i][j][r] + bs;
                int rr = row + r;
                if (EPI & 1) v = gelu_fast(v);
                if (EPI & 2) v += resid[(size_t)rr * N + col];
                if (EPI & 4) Cf[(size_t)rr * N + col] = v;
                if (EPI & 8) Cb[(size_t)rr * N + col] = f2bf(v);
            }
        }
    }
}

// ---------------- V transpose: qkv[.,2048+h*64+d] -> vT[bh][d][t] ----------------
__global__ __launch_bounds__(256) void vtrans_kernel(const unsigned short* __restrict__ qkv,
                                                     unsigned short* __restrict__ vT) {
    __shared__ unsigned short tile[64 * 72];
    int tid = threadIdx.x;
    int bh = blockIdx.y, b = bh >> 4, h = bh & 15;
    int t0 = blockIdx.x * 64;
    const unsigned short* vsrc = qkv + (size_t)b * SEQ * QKV_N + 2 * E_DIM + h * HD;
#pragma unroll
    for (int p = 0; p < 2; ++p) {
        int idx = p * 256 + tid;
        int row = idx >> 3, col = (idx & 7) * 8;
        *(shortx8*)&tile[row * 72 + col] =
            *(const shortx8*)&vsrc[(size_t)(t0 + row) * QKV_N + col];
    }
    __syncthreads();
    int d = tid >> 2, tch = (tid & 3) * 16;
    unsigned short* dst = vT + (size_t)bh * HD * SEQ + (size_t)d * SEQ + t0 + tch;
    shortx8 a0, a1;
#pragma unroll
    for (int j = 0; j < 8; ++j) a0[j] = (short)tile[(tch + j) * 72 + d];
#pragma unroll
    for (int j = 0; j < 8; ++j) a1[j] = (short)tile[(tch + 8 + j) * 72 + d];
    *(shortx8*)&dst[0] = a0;
    *(shortx8*)&dst[8] = a1;
}

// ---------------- Flash attention: 64-key tiles, paired q-tiles, swizzled LDS ----------------
__global__ __launch_bounds__(256) void attn_kernel(
        const unsigned short* __restrict__ qkv, const unsigned short* __restrict__ vT,
        unsigned short* __restrict__ out) {
    __shared__ unsigned short kt[64 * 64];
    __shared__ unsigned short vt[64 * 64];
    __shared__ unsigned short ps[4][16 * 64];
    int tid = threadIdx.x;
    int wave = tid >> 6, lane = tid & 63, l15 = lane & 15, quad = lane >> 4;
    int bh = blockIdx.y, b = bh >> 4, h = bh & 15;
    const unsigned short* qbase = qkv + (size_t)b * SEQ * QKV_N + h * HD;
    const unsigned short* kbase = qbase + E_DIM;
    const unsigned short* vtb = vT + (size_t)bh * HD * SEQ;

    int srl = lane >> 3;
    int scg = (lane & 7) ^ srl;

    const float scale = 0.125f * 1.44269504f;

    for (int pass = 0; pass < 2; ++pass) {
        int qt = (pass == 0) ? blockIdx.x : (15 - blockIdx.x);
        int q0 = qt * 64;
        int qrow = q0 + wave * 16;

        shortx8 qa0 = *(const shortx8*)&qbase[(size_t)(qrow + l15) * QKV_N + quad * 8];
        shortx8 qa1 = *(const shortx8*)&qbase[(size_t)(qrow + l15) * QKV_N + 32 + quad * 8];

        floatx4 o[4];
        for (int d = 0; d < 4; ++d) o[d] = (floatx4)0.f;
        float mrun[4], lrun[4];
        for (int r = 0; r < 4; ++r) { mrun[r] = -1e30f; lrun[r] = 0.f; }

        int ntile = qt + 1;
        for (int t = 0; t < ntile; ++t) {
            int s0 = t * 64;
            __syncthreads();
#pragma unroll
            for (int p = 0; p < 2; ++p) {
                int rbase = p * 32 + wave * 8;
                __builtin_amdgcn_global_load_lds(
                    (gas_ptr)&kbase[(size_t)(s0 + rbase + srl) * QKV_N + scg * 8],
                    (las_ptr)&kt[rbase * 64], 16, 0, 0);
                __builtin_amdgcn_global_load_lds(
                    (gas_ptr)&vtb[(size_t)(rbase + srl) * SEQ + s0 + scg * 8],
                    (las_ptr)&vt[rbase * 64], 16, 0, 0);
            }
            __syncthreads();

            floatx4 sfr[4];
#pragma unroll
            for (int ct = 0; ct < 4; ++ct) {
                int R = ct * 16 + l15;
                int sc0 = quad ^ (R & 7), sc1 = (4 + quad) ^ (R & 7);
                shortx8 kb0 = *(const shortx8*)&kt[(R * 8 + sc0) * 8];
                shortx8 kb1 = *(const shortx8*)&kt[(R * 8 + sc1) * 8];
                floatx4 s4 = (floatx4)0.f;
                s4 = __builtin_amdgcn_mfma_f32_16x16x32_bf16(qa0, kb0, s4, 0, 0, 0);
                s4 = __builtin_amdgcn_mfma_f32_16x16x32_bf16(qa1, kb1, s4, 0, 0, 0);
                sfr[ct] = s4;
            }

            bool masked = (t == ntile - 1);
#pragma unroll
            for (int r = 0; r < 4; ++r) {
                int qg = qrow + quad * 4 + r;
                float sv[4];
                float mx = mrun[r];
#pragma unroll
                for (int ct = 0; ct < 4; ++ct) {
                    float v = sfr[ct][r] * scale;
                    if (masked && (s0 + ct * 16 + l15 > qg)) v = -1e30f;
                    sv[ct] = v;
                    mx = fmaxf(mx, v);
                }
                for (int mm = 8; mm; mm >>= 1) mx = fmaxf(mx, __shfl_xor(mx, mm));
                float alpha = exp2f(mrun[r] - mx);
                mrun[r] = mx;
                float sum = 0.f;
                float pv[4];
#pragma unroll
                for (int ct = 0; ct < 4; ++ct) { pv[ct] = exp2f(sv[ct] - mx); sum += pv[ct]; }
                for (int mm = 8; mm; mm >>= 1) sum += __shfl_xor(sum, mm);
                lrun[r] = lrun[r] * alpha + sum;
#pragma unroll
                for (int d = 0; d < 4; ++d) o[d][r] *= alpha;
                int row = quad * 4 + r;
#pragma unroll
                for (int ct = 0; ct < 4; ++ct) {
                    int g = ct * 2 + (l15 >> 3);
                    int sc = g ^ (row & 7);
                    ps[wave][row * 64 + sc * 8 + (l15 & 7)] = f2bf(pv[ct]);
                }
            }
            shortx8 pa0, pa1;
            {
                int sc0 = quad ^ (l15 & 7), sc1 = (4 + quad) ^ (l15 & 7);
                pa0 = *(const shortx8*)&ps[wave][(l15 * 8 + sc0) * 8];
                pa1 = *(const shortx8*)&ps[wave][(l15 * 8 + sc1) * 8];
            }
#pragma unroll
            for (int d = 0; d < 4; ++d) {
                int R = d * 16 + l15;
                int sc0 = quad ^ (R & 7), sc1 = (4 + quad) ^ (R & 7);
                shortx8 vb0 = *(const shortx8*)&vt[(R * 8 + sc0) * 8];
                shortx8 vb1 = *(const shortx8*)&vt[(R * 8 + sc1) * 8];
                o[d] = __builtin_amdgcn_mfma_f32_16x16x32_bf16(pa0, vb0, o[d], 0, 0, 0);
                o[d] = __builtin_amdgcn_mfma_f32_16x16x32_bf16(pa1, vb1, o[d], 0, 0, 0);
            }
        }

#pragma unroll
        for (int r = 0; r < 4; ++r) {
            float inv = 1.0f / lrun[r];
            int m = (b << 10) + qrow + quad * 4 + r;
#pragma unroll
            for (int d = 0; d < 4; ++d)
                out[(size_t)m * E_DIM + h * HD + d * 16 + l15] = f2bf(o[d][r] * inv);
        }
    }
}

// ---------------- launch ----------------
extern "C" void kernel_launch(void* const* d_in, const int* in_sizes, int n_in,
                              void* d_out, int out_size, void* d_ws, size_t ws_size,
                              hipStream_t stream) {
    const float* x     = (const float*)d_in[0];
    const float* ln1_w = (const float*)d_in[1];
    const float* ln1_b = (const float*)d_in[2];
    const float* ln2_w = (const float*)d_in[3];
    const float* ln2_b = (const float*)d_in[4];
    const float* qkv_w = (const float*)d_in[5];
    const float* qkv_b = (const float*)d_in[6];
    const float* out_w = (const float*)d_in[7];
    const float* out_b = (const float*)d_in[8];
    const float* fc1_w = (const float*)d_in[9];
    const float* fc1_b = (const float*)d_in[10];
    const float* fc2_w = (const float*)d_in[11];
    const float* fc2_b = (const float*)d_in[12];

    char* ws = (char*)d_ws;
    size_t off = 0;
    auto alloc = [&](size_t bytes) { char* p = ws + off; off += bytes; return p; };
    unsigned short* wq   = (unsigned short*)alloc((size_t)3 * E_DIM * E_DIM * 2);
    unsigned short* wo   = (unsigned short*)alloc((size_t)E_DIM * E_DIM * 2);
    unsigned short* w1   = (unsigned short*)alloc((size_t)F_DIM * E_DIM * 2);
    unsigned short* w2   = (unsigned short*)alloc((size_t)E_DIM * F_DIM * 2);
    unsigned short* h1   = (unsigned short*)alloc((size_t)MROWS * E_DIM * 2);
    unsigned short* qkvb = (unsigned short*)alloc((size_t)MROWS * QKV_N * 2);
    unsigned short* vT   = (unsigned short*)alloc((size_t)BATCH * NH * HD * SEQ * 2);
    unsigned short* attn = (unsigned short*)alloc((size_t)MROWS * E_DIM * 2);
    float*          x1   = (float*)alloc((size_t)MROWS * E_DIM * 4);
    unsigned short* h2   = (unsigned short*)alloc((size_t)MROWS * E_DIM * 2);
    unsigned short* g    = (unsigned short*)alloc((size_t)MROWS * F_DIM * 2);

    {
        int n;
        n = 3 * E_DIM * E_DIM; f2b_kernel<<<(n + 255) / 256, 256, 0, stream>>>(qkv_w, wq, n);
        n = E_DIM * E_DIM;     f2b_kernel<<<(n + 255) / 256, 256, 0, stream>>>(out_w, wo, n);
        n = F_DIM * E_DIM;     f2b_kernel<<<(n + 255) / 256, 256, 0, stream>>>(fc1_w, w1, n);
        n = E_DIM * F_DIM;     f2b_kernel<<<(n + 255) / 256, 256, 0, stream>>>(fc2_w, w2, n);
    }

    ln_kernel<<<MROWS, 256, 0, stream>>>(x, ln1_w, ln1_b, h1);
    gemm_bt<8><<<dim3(QKV_N / TN, MROWS / TM), 256, 0, stream>>>(
        h1, wq, qkv_b, nullptr, nullptr, qkvb, MROWS, QKV_N, E_DIM);
    vtrans_kernel<<<dim3(SEQ / 64, BATCH * NH), 256, 0, stream>>>(qkvb, vT);
    attn_kernel<<<dim3(8, BATCH * NH), 256, 0, stream>>>(qkvb, vT, attn);
    // out proj + residual(x) -> x1 fp32   (N=1024: 128x64 tiles, 512 blocks)
    gemm_n64<2 | 4><<<dim3(E_DIM / 64, MROWS / TM), 256, 0, stream>>>(
        attn, wo, out_b, x, x1, nullptr, MROWS, E_DIM, E_DIM);
    ln_kernel<<<MROWS, 256, 0, stream>>>(x1, ln2_w, ln2_b, h2);
    gemm_bt<1 | 8><<<dim3(F_DIM / TN, MROWS / TM), 256, 0, stream>>>(
        h2, w1, fc1_b, nullptr, nullptr, g, MROWS, F_DIM, E_DIM);
    // FC2 + residual(x1) -> d_out fp32   (N=1024: 128x64 tiles, 512 blocks)
    gemm_n64<2 | 4><<<dim3(E_DIM / 64, MROWS / TM), 256, 0, stream>>>(
        g, w2, fc2_b, x1, (float*)d_out, nullptr, MROWS, E_DIM, F_DIM);
}

// Round 8
// 358.332 us; speedup vs baseline: 1.0671x; 1.0290x over previous
//
#include <hip/hip_runtime.h>

typedef float floatx4 __attribute__((ext_vector_type(4)));
typedef short shortx8 __attribute__((ext_vector_type(8)));

#define E_DIM 1024
#define F_DIM 4096
#define BATCH 4
#define SEQ 1024
#define NH 16
#define HD 64
#define MROWS (BATCH*SEQ)   // 4096
#define QKV_N (3*E_DIM)     // 3072

typedef const __attribute__((address_space(1))) unsigned int* gas_ptr;
typedef __attribute__((address_space(3))) unsigned int* las_ptr;

__device__ __forceinline__ unsigned short f2bf(float f) {
    union { float f; unsigned u; } un; un.f = f;
    unsigned u = un.u;
    u += 0x7fffu + ((u >> 16) & 1u);   // RNE
    return (unsigned short)(u >> 16);
}

// tanh-form GELU via sigmoid: u = sqrt(2/pi)*(x+0.044715x^3); gelu = x*sigmoid(2u)
__device__ __forceinline__ float gelu_fast(float v) {
    float u = 0.7978845608f * (v + 0.044715f * v * v * v);
    return v / (1.0f + __builtin_exp2f(-2.885390082f * u));  // 2*log2(e)*u
}

// XCD-aware tile remap, m-fastest within XCD (see R6/R7 notes).
__device__ __forceinline__ void xcd_remap(int& m_idx, int& n_idx) {
    int nt = gridDim.x;
    int mt_x = gridDim.y >> 3;
    int lin = blockIdx.y * nt + blockIdx.x;
    int xcd = lin & 7, loc = lin >> 3;
    int n = loc / mt_x;
    int m_local = loc - n * mt_x;
    m_idx = xcd * mt_x + m_local;
    n_idx = n;
}

// ---------------- fp32 -> bf16 convert (weights) ----------------
__global__ void f2b_kernel(const float* __restrict__ in, unsigned short* __restrict__ out, int n) {
    int i = blockIdx.x * 256 + threadIdx.x;
    if (i < n) out[i] = f2bf(in[i]);
}

// ---------------- LayerNorm (row=1024), fp32 in, bf16 out ----------------
__global__ __launch_bounds__(256) void ln_kernel(const float* __restrict__ x,
                                                 const float* __restrict__ w,
                                                 const float* __restrict__ b,
                                                 unsigned short* __restrict__ out) {
    int row = blockIdx.x;
    const float* xr = x + (size_t)row * E_DIM;
    float v[4];
    float s = 0.f, ss = 0.f;
    for (int i = 0; i < 4; ++i) {
        v[i] = xr[threadIdx.x + i * 256];
        s += v[i]; ss += v[i] * v[i];
    }
    for (int m = 32; m; m >>= 1) { s += __shfl_xor(s, m); ss += __shfl_xor(ss, m); }
    __shared__ float red[8];
    int wave = threadIdx.x >> 6;
    if ((threadIdx.x & 63) == 0) { red[wave] = s; red[wave + 4] = ss; }
    __syncthreads();
    s = red[0] + red[1] + red[2] + red[3];
    ss = red[4] + red[5] + red[6] + red[7];
    float mu = s * (1.0f / E_DIM);
    float var = ss * (1.0f / E_DIM) - mu * mu;
    float rs = rsqrtf(var + 1e-5f);
    for (int i = 0; i < 4; ++i) {
        int c = threadIdx.x + i * 256;
        out[(size_t)row * E_DIM + c] = f2bf((v[i] - mu) * rs * w[c] + b[c]);
    }
}

// ---------------- GEMM 128x128 (m97 structure) — for N>=3072 GEMMs ----------------
#define TM 128
#define TN 128
#define BK 64

template<int EPI>
__global__ __launch_bounds__(256) void gemm_bt(
        const unsigned short* __restrict__ A, const unsigned short* __restrict__ Bw,
        const float* __restrict__ bias, const float* __restrict__ resid,
        float* __restrict__ Cf, unsigned short* __restrict__ Cb,
        int M, int N, int K) {
    __shared__ unsigned short sA[TM * BK];
    __shared__ unsigned short sB[TN * BK];
    int tid = threadIdx.x;
    int wave = tid >> 6, lane = tid & 63;
    int m_idx, n_idx;
    xcd_remap(m_idx, n_idx);
    int n0 = n_idx * TN, m0 = m_idx * TM;
    int wm = (wave & 1) * 64, wn = (wave >> 1) * 64;
    int l15 = lane & 15, quad = lane >> 4;

    int srow = wave * 32 + (lane >> 3);
    int scg  = (lane & 7) ^ (srow & 7);
    const unsigned short* Ag = A  + (size_t)(m0 + srow) * K + scg * 8;
    const unsigned short* Bg = Bw + (size_t)(n0 + srow) * K + scg * 8;

    floatx4 acc[4][4];
#pragma unroll
    for (int i = 0; i < 4; ++i)
#pragma unroll
        for (int j = 0; j < 4; ++j) acc[i][j] = (floatx4)0.f;

    for (int k0 = 0; k0 < K; k0 += BK) {
        __syncthreads();
#pragma unroll
        for (int p = 0; p < 4; ++p) {
            __builtin_amdgcn_global_load_lds((gas_ptr)(Ag + k0 + p * 8 * K),
                (las_ptr)&sA[(wave * 32 + p * 8) * BK], 16, 0, 0);
            __builtin_amdgcn_global_load_lds((gas_ptr)(Bg + k0 + p * 8 * K),
                (las_ptr)&sB[(wave * 32 + p * 8) * BK], 16, 0, 0);
        }
        __syncthreads();
#pragma unroll
        for (int kk8 = 0; kk8 < 8; kk8 += 4) {
            shortx8 af[4], bfr[4];
#pragma unroll
            for (int i = 0; i < 4; ++i) {
                int R = wm + i * 16 + l15;
                int sc = (quad + kk8) ^ (R & 7);
                af[i] = *(const shortx8*)&sA[(R * 8 + sc) * 8];
            }
#pragma unroll
            for (int j = 0; j < 4; ++j) {
                int R = wn + j * 16 + l15;
                int sc = (quad + kk8) ^ (R & 7);
                bfr[j] = *(const shortx8*)&sB[(R * 8 + sc) * 8];
            }
#pragma unroll
            for (int i = 0; i < 4; ++i)
#pragma unroll
                for (int j = 0; j < 4; ++j)
                    acc[i][j] = __builtin_amdgcn_mfma_f32_16x16x32_bf16(af[i], bfr[j], acc[i][j], 0, 0, 0);
        }
    }

#pragma unroll
    for (int i = 0; i < 4; ++i) {
        int row = m0 + wm + i * 16 + quad * 4;
#pragma unroll
        for (int j = 0; j < 4; ++j) {
            int col = n0 + wn + j * 16 + l15;
            float bs = bias[col];
#pragma unroll
            for (int r = 0; r < 4; ++r) {
                float v = acc[i][j][r] + bs;
                int rr = row + r;
                if (EPI & 1) v = gelu_fast(v);
                if (EPI & 2) v += resid[(size_t)rr * N + col];
                if (EPI & 4) Cf[(size_t)rr * N + col] = v;
                if (EPI & 8) Cb[(size_t)rr * N + col] = f2bf(v);
            }
        }
    }
}

// ---------------- GEMM 128x64, explicit 2-deep LDS pipeline (raw s_barrier +
// hand vmcnt) — for N=1024 GEMMs. Per-wave stage = 6 vmem ops; consume-wait
// vmcnt(6) retires exactly the tile being computed while the next stays in
// flight across the barrier (m139 pattern). ----------------
template<int EPI>
__global__ __launch_bounds__(256) void gemm_n64(
        const unsigned short* __restrict__ A, const unsigned short* __restrict__ Bw,
        const float* __restrict__ bias, const float* __restrict__ resid,
        float* __restrict__ Cf, unsigned short* __restrict__ Cb,
        int M, int N, int K) {
    __shared__ unsigned short sA[2][TM * BK];
    __shared__ unsigned short sB[2][64 * BK];
    int tid = threadIdx.x;
    int wave = tid >> 6, lane = tid & 63;
    int m_idx, n_idx;
    xcd_remap(m_idx, n_idx);
    int n0 = n_idx * 64, m0 = m_idx * TM;
    int wm = (wave & 1) * 64, wn = (wave >> 1) * 32;
    int l15 = lane & 15, quad = lane >> 4;

    int srow = wave * 32 + (lane >> 3);
    int scg  = (lane & 7) ^ (srow & 7);
    const unsigned short* Ag = A + (size_t)(m0 + srow) * K + scg * 8;
    int srB  = wave * 16 + (lane >> 3);
    int scgB = (lane & 7) ^ (srB & 7);
    const unsigned short* Bg = Bw + (size_t)(n0 + srB) * K + scgB * 8;

    floatx4 acc[4][2];
#pragma unroll
    for (int i = 0; i < 4; ++i)
#pragma unroll
        for (int j = 0; j < 2; ++j) acc[i][j] = (floatx4)0.f;

    auto stage = [&](int kt, int bsel) {
        int k0 = kt * BK;
#pragma unroll
        for (int p = 0; p < 4; ++p)
            __builtin_amdgcn_global_load_lds((gas_ptr)(Ag + k0 + p * 8 * K),
                (las_ptr)&sA[bsel][(wave * 32 + p * 8) * BK], 16, 0, 0);
#pragma unroll
        for (int p = 0; p < 2; ++p)
            __builtin_amdgcn_global_load_lds((gas_ptr)(Bg + k0 + p * 8 * K),
                (las_ptr)&sB[bsel][(wave * 16 + p * 8) * BK], 16, 0, 0);
    };

    int T = K / BK;   // >= 16 for all uses
    stage(0, 0);
    stage(1, 1);
    for (int i = 0; i < T; ++i) {
        if (i + 1 < T) { asm volatile("s_waitcnt vmcnt(6)" ::: "memory"); }
        else           { asm volatile("s_waitcnt vmcnt(0)" ::: "memory"); }
        __builtin_amdgcn_s_barrier();
        int bs = i & 1;
#pragma unroll
        for (int kk8 = 0; kk8 < 8; kk8 += 4) {
            shortx8 af[4], bfr[2];
#pragma unroll
            for (int ii = 0; ii < 4; ++ii) {
                int R = wm + ii * 16 + l15;
                int sc = (quad + kk8) ^ (R & 7);
                af[ii] = *(const shortx8*)&sA[bs][(R * 8 + sc) * 8];
            }
#pragma unroll
            for (int j = 0; j < 2; ++j) {
                int R = wn + j * 16 + l15;
                int sc = (quad + kk8) ^ (R & 7);
                bfr[j] = *(const shortx8*)&sB[bs][(R * 8 + sc) * 8];
            }
#pragma unroll
            for (int ii = 0; ii < 4; ++ii)
#pragma unroll
                for (int j = 0; j < 2; ++j)
                    acc[ii][j] = __builtin_amdgcn_mfma_f32_16x16x32_bf16(af[ii], bfr[j], acc[ii][j], 0, 0, 0);
        }
        __builtin_amdgcn_s_barrier();
        if (i + 2 < T) stage(i + 2, bs);
    }

#pragma unroll
    for (int i = 0; i < 4; ++i) {
        int row = m0 + wm + i * 16 + quad * 4;
#pragma unroll
        for (int j = 0; j < 2; ++j) {
            int col = n0 + wn + j * 16 + l15;
            float bs = bias[col];
#pragma unroll
            for (int r = 0; r < 4; ++r) {
                float v = acc[i][j][r] + bs;
                int rr = row + r;
                if (EPI & 1) v = gelu_fast(v);
                if (EPI & 2) v += resid[(size_t)rr * N + col];
                if (EPI & 4) Cf[(size_t)rr * N + col] = v;
                if (EPI & 8) Cb[(size_t)rr * N + col] = f2bf(v);
            }
        }
    }
}

// ---------------- V transpose: qkv[.,2048+h*64+d] -> vT[bh][d][t] ----------------
__global__ __launch_bounds__(256) void vtrans_kernel(const unsigned short* __restrict__ qkv,
                                                     unsigned short* __restrict__ vT) {
    __shared__ unsigned short tile[64 * 72];
    int tid = threadIdx.x;
    int bh = blockIdx.y, b = bh >> 4, h = bh & 15;
    int t0 = blockIdx.x * 64;
    const unsigned short* vsrc = qkv + (size_t)b * SEQ * QKV_N + 2 * E_DIM + h * HD;
#pragma unroll
    for (int p = 0; p < 2; ++p) {
        int idx = p * 256 + tid;
        int row = idx >> 3, col = (idx & 7) * 8;
        *(shortx8*)&tile[row * 72 + col] =
            *(const shortx8*)&vsrc[(size_t)(t0 + row) * QKV_N + col];
    }
    __syncthreads();
    int d = tid >> 2, tch = (tid & 3) * 16;
    unsigned short* dst = vT + (size_t)bh * HD * SEQ + (size_t)d * SEQ + t0 + tch;
    shortx8 a0, a1;
#pragma unroll
    for (int j = 0; j < 8; ++j) a0[j] = (short)tile[(tch + j) * 72 + d];
#pragma unroll
    for (int j = 0; j < 8; ++j) a1[j] = (short)tile[(tch + 8 + j) * 72 + d];
    *(shortx8*)&dst[0] = a0;
    *(shortx8*)&dst[8] = a1;
}

// ---------------- Flash attention: 64-key tiles, paired q-tiles, swizzled LDS ----------------
__global__ __launch_bounds__(256) void attn_kernel(
        const unsigned short* __restrict__ qkv, const unsigned short* __restrict__ vT,
        unsigned short* __restrict__ out) {
    __shared__ unsigned short kt[64 * 64];
    __shared__ unsigned short vt[64 * 64];
    __shared__ unsigned short ps[4][16 * 64];
    int tid = threadIdx.x;
    int wave = tid >> 6, lane = tid & 63, l15 = lane & 15, quad = lane >> 4;
    int bh = blockIdx.y, b = bh >> 4, h = bh & 15;
    const unsigned short* qbase = qkv + (size_t)b * SEQ * QKV_N + h * HD;
    const unsigned short* kbase = qbase + E_DIM;
    const unsigned short* vtb = vT + (size_t)bh * HD * SEQ;

    int srl = lane >> 3;
    int scg = (lane & 7) ^ srl;

    const float scale = 0.125f * 1.44269504f;

    for (int pass = 0; pass < 2; ++pass) {
        int qt = (pass == 0) ? blockIdx.x : (15 - blockIdx.x);
        int q0 = qt * 64;
        int qrow = q0 + wave * 16;

        shortx8 qa0 = *(const shortx8*)&qbase[(size_t)(qrow + l15) * QKV_N + quad * 8];
        shortx8 qa1 = *(const shortx8*)&qbase[(size_t)(qrow + l15) * QKV_N + 32 + quad * 8];

        floatx4 o[4];
        for (int d = 0; d < 4; ++d) o[d] = (floatx4)0.f;
        float mrun[4], lrun[4];
        for (int r = 0; r < 4; ++r) { mrun[r] = -1e30f; lrun[r] = 0.f; }

        int ntile = qt + 1;
        for (int t = 0; t < ntile; ++t) {
            int s0 = t * 64;
            __syncthreads();
#pragma unroll
            for (int p = 0; p < 2; ++p) {
                int rbase = p * 32 + wave * 8;
                __builtin_amdgcn_global_load_lds(
                    (gas_ptr)&kbase[(size_t)(s0 + rbase + srl) * QKV_N + scg * 8],
                    (las_ptr)&kt[rbase * 64], 16, 0, 0);
                __builtin_amdgcn_global_load_lds(
                    (gas_ptr)&vtb[(size_t)(rbase + srl) * SEQ + s0 + scg * 8],
                    (las_ptr)&vt[rbase * 64], 16, 0, 0);
            }
            __syncthreads();

            floatx4 sfr[4];
#pragma unroll
            for (int ct = 0; ct < 4; ++ct) {
                int R = ct * 16 + l15;
                int sc0 = quad ^ (R & 7), sc1 = (4 + quad) ^ (R & 7);
                shortx8 kb0 = *(const shortx8*)&kt[(R * 8 + sc0) * 8];
                shortx8 kb1 = *(const shortx8*)&kt[(R * 8 + sc1) * 8];
                floatx4 s4 = (floatx4)0.f;
                s4 = __builtin_amdgcn_mfma_f32_16x16x32_bf16(qa0, kb0, s4, 0, 0, 0);
                s4 = __builtin_amdgcn_mfma_f32_16x16x32_bf16(qa1, kb1, s4, 0, 0, 0);
                sfr[ct] = s4;
            }

            bool masked = (t == ntile - 1);
#pragma unroll
            for (int r = 0; r < 4; ++r) {
                int qg = qrow + quad * 4 + r;
                float sv[4];
                float mx = mrun[r];
#pragma unroll
                for (int ct = 0; ct < 4; ++ct) {
                    float v = sfr[ct][r] * scale;
                    if (masked && (s0 + ct * 16 + l15 > qg)) v = -1e30f;
                    sv[ct] = v;
                    mx = fmaxf(mx, v);
                }
                for (int mm = 8; mm; mm >>= 1) mx = fmaxf(mx, __shfl_xor(mx, mm));
                float alpha = exp2f(mrun[r] - mx);
                mrun[r] = mx;
                float sum = 0.f;
                float pv[4];
#pragma unroll
                for (int ct = 0; ct < 4; ++ct) { pv[ct] = exp2f(sv[ct] - mx); sum += pv[ct]; }
                for (int mm = 8; mm; mm >>= 1) sum += __shfl_xor(sum, mm);
                lrun[r] = lrun[r] * alpha + sum;
#pragma unroll
                for (int d = 0; d < 4; ++d) o[d][r] *= alpha;
                int row = quad * 4 + r;
#pragma unroll
                for (int ct = 0; ct < 4; ++ct) {
                    int g = ct * 2 + (l15 >> 3);
                    int sc = g ^ (row & 7);
                    ps[wave][row * 64 + sc * 8 + (l15 & 7)] = f2bf(pv[ct]);
                }
            }
            shortx8 pa0, pa1;
            {
                int sc0 = quad ^ (l15 & 7), sc1 = (4 + quad) ^ (l15 & 7);
                pa0 = *(const shortx8*)&ps[wave][(l15 * 8 + sc0) * 8];
                pa1 = *(const shortx8*)&ps[wave][(l15 * 8 + sc1) * 8];
            }
#pragma unroll
            for (int d = 0; d < 4; ++d) {
                int R = d * 16 + l15;
                int sc0 = quad ^ (R & 7), sc1 = (4 + quad) ^ (R & 7);
                shortx8 vb0 = *(const shortx8*)&vt[(R * 8 + sc0) * 8];
                shortx8 vb1 = *(const shortx8*)&vt[(R * 8 + sc1) * 8];
                o[d] = __builtin_amdgcn_mfma_f32_16x16x32_bf16(pa0, vb0, o[d], 0, 0, 0);
                o[d] = __builtin_amdgcn_mfma_f32_16x16x32_bf16(pa1, vb1, o[d], 0, 0, 0);
            }
        }

#pragma unroll
        for (int r = 0; r < 4; ++r) {
            float inv = 1.0f / lrun[r];
            int m = (b << 10) + qrow + quad * 4 + r;
#pragma unroll
            for (int d = 0; d < 4; ++d)
                out[(size_t)m * E_DIM + h * HD + d * 16 + l15] = f2bf(o[d][r] * inv);
        }
    }
}

// ---------------- launch ----------------
extern "C" void kernel_launch(void* const* d_in, const int* in_sizes, int n_in,
                              void* d_out, int out_size, void* d_ws, size_t ws_size,
                              hipStream_t stream) {
    const float* x     = (const float*)d_in[0];
    const float* ln1_w = (const float*)d_in[1];
    const float* ln1_b = (const float*)d_in[2];
    const float* ln2_w = (const float*)d_in[3];
    const float* ln2_b = (const float*)d_in[4];
    const float* qkv_w = (const float*)d_in[5];
    const float* qkv_b = (const float*)d_in[6];
    const float* out_w = (const float*)d_in[7];
    const float* out_b = (const float*)d_in[8];
    const float* fc1_w = (const float*)d_in[9];
    const float* fc1_b = (const float*)d_in[10];
    const float* fc2_w = (const float*)d_in[11];
    const float* fc2_b = (const float*)d_in[12];

    char* ws = (char*)d_ws;
    size_t off = 0;
    auto alloc = [&](size_t bytes) { char* p = ws + off; off += bytes; return p; };
    unsigned short* wq   = (unsigned short*)alloc((size_t)3 * E_DIM * E_DIM * 2);
    unsigned short* wo   = (unsigned short*)alloc((size_t)E_DIM * E_DIM * 2);
    unsigned short* w1   = (unsigned short*)alloc((size_t)F_DIM * E_DIM * 2);
    unsigned short* w2   = (unsigned short*)alloc((size_t)E_DIM * F_DIM * 2);
    unsigned short* h1   = (unsigned short*)alloc((size_t)MROWS * E_DIM * 2);
    unsigned short* qkvb = (unsigned short*)alloc((size_t)MROWS * QKV_N * 2);
    unsigned short* vT   = (unsigned short*)alloc((size_t)BATCH * NH * HD * SEQ * 2);
    unsigned short* attn = (unsigned short*)alloc((size_t)MROWS * E_DIM * 2);
    float*          x1   = (float*)alloc((size_t)MROWS * E_DIM * 4);
    unsigned short* h2   = (unsigned short*)alloc((size_t)MROWS * E_DIM * 2);
    unsigned short* g    = (unsigned short*)alloc((size_t)MROWS * F_DIM * 2);

    {
        int n;
        n = 3 * E_DIM * E_DIM; f2b_kernel<<<(n + 255) / 256, 256, 0, stream>>>(qkv_w, wq, n);
        n = E_DIM * E_DIM;     f2b_kernel<<<(n + 255) / 256, 256, 0, stream>>>(out_w, wo, n);
        n = F_DIM * E_DIM;     f2b_kernel<<<(n + 255) / 256, 256, 0, stream>>>(fc1_w, w1, n);
        n = E_DIM * F_DIM;     f2b_kernel<<<(n + 255) / 256, 256, 0, stream>>>(fc2_w, w2, n);
    }

    ln_kernel<<<MROWS, 256, 0, stream>>>(x, ln1_w, ln1_b, h1);
    gemm_bt<8><<<dim3(QKV_N / TN, MROWS / TM), 256, 0, stream>>>(
        h1, wq, qkv_b, nullptr, nullptr, qkvb, MROWS, QKV_N, E_DIM);
    vtrans_kernel<<<dim3(SEQ / 64, BATCH * NH), 256, 0, stream>>>(qkvb, vT);
    attn_kernel<<<dim3(8, BATCH * NH), 256, 0, stream>>>(qkvb, vT, attn);
    // out proj + residual(x) -> x1 fp32   (N=1024: 128x64 tiles, 512 blocks)
    gemm_n64<2 | 4><<<dim3(E_DIM / 64, MROWS / TM), 256, 0, stream>>>(
        attn, wo, out_b, x, x1, nullptr, MROWS, E_DIM, E_DIM);
    ln_kernel<<<MROWS, 256, 0, stream>>>(x1, ln2_w, ln2_b, h2);
    gemm_bt<1 | 8><<<dim3(F_DIM / TN, MROWS / TM), 256, 0, stream>>>(
        h2, w1, fc1_b, nullptr, nullptr, g, MROWS, F_DIM, E_DIM);
    // FC2 + residual(x1) -> d_out fp32   (N=1024: 128x64 tiles, 512 blocks)
    gemm_n64<2 | 4><<<dim3(E_DIM / 64, MROWS / TM), 256, 0, stream>>>(
        g, w2, fc2_b, x1, (float*)d_out, nullptr, MROWS, E_DIM, F_DIM);
}

// Round 9
// 351.029 us; speedup vs baseline: 1.0893x; 1.0208x over previous
//
#include <hip/hip_runtime.h>

typedef float floatx4 __attribute__((ext_vector_type(4)));
typedef short shortx8 __attribute__((ext_vector_type(8)));

#define E_DIM 1024
#define F_DIM 4096
#define BATCH 4
#define SEQ 1024
#define NH 16
#define HD 64
#define MROWS (BATCH*SEQ)   // 4096
#define QKV_N (3*E_DIM)     // 3072

typedef const __attribute__((address_space(1))) unsigned int* gas_ptr;
typedef __attribute__((address_space(3))) unsigned int* las_ptr;

__device__ __forceinline__ unsigned short f2bf(float f) {
    union { float f; unsigned u; } un; un.f = f;
    unsigned u = un.u;
    u += 0x7fffu + ((u >> 16) & 1u);   // RNE
    return (unsigned short)(u >> 16);
}

// tanh-form GELU, division replaced by v_rcp_f32 (1 inst, ~1 ulp)
__device__ __forceinline__ float gelu_fast(float v) {
    float u = 0.7978845608f * (v + 0.044715f * v * v * v);
    float t = __builtin_exp2f(-2.885390082f * u);   // 2*log2(e)*u
    return v * __builtin_amdgcn_rcpf(1.0f + t);
}

// XCD-aware tile remap, m-fastest within XCD (see R6/R7 notes).
__device__ __forceinline__ void xcd_remap(int& m_idx, int& n_idx) {
    int nt = gridDim.x;
    int mt_x = gridDim.y >> 3;
    int lin = blockIdx.y * nt + blockIdx.x;
    int xcd = lin & 7, loc = lin >> 3;
    int n = loc / mt_x;
    int m_local = loc - n * mt_x;
    m_idx = xcd * mt_x + m_local;
    n_idx = n;
}

// ---------------- fp32 -> bf16 convert (weights) ----------------
__global__ void f2b_kernel(const float* __restrict__ in, unsigned short* __restrict__ out, int n) {
    int i = blockIdx.x * 256 + threadIdx.x;
    if (i < n) out[i] = f2bf(in[i]);
}

// ---------------- LayerNorm (row=1024), fp32 in, bf16 out ----------------
__global__ __launch_bounds__(256) void ln_kernel(const float* __restrict__ x,
                                                 const float* __restrict__ w,
                                                 const float* __restrict__ b,
                                                 unsigned short* __restrict__ out) {
    int row = blockIdx.x;
    const float* xr = x + (size_t)row * E_DIM;
    float v[4];
    float s = 0.f, ss = 0.f;
    for (int i = 0; i < 4; ++i) {
        v[i] = xr[threadIdx.x + i * 256];
        s += v[i]; ss += v[i] * v[i];
    }
    for (int m = 32; m; m >>= 1) { s += __shfl_xor(s, m); ss += __shfl_xor(ss, m); }
    __shared__ float red[8];
    int wave = threadIdx.x >> 6;
    if ((threadIdx.x & 63) == 0) { red[wave] = s; red[wave + 4] = ss; }
    __syncthreads();
    s = red[0] + red[1] + red[2] + red[3];
    ss = red[4] + red[5] + red[6] + red[7];
    float mu = s * (1.0f / E_DIM);
    float var = ss * (1.0f / E_DIM) - mu * mu;
    float rs = rsqrtf(var + 1e-5f);
    for (int i = 0; i < 4; ++i) {
        int c = threadIdx.x + i * 256;
        out[(size_t)row * E_DIM + c] = f2bf((v[i] - mu) * rs * w[c] + b[c]);
    }
}

// ---------------- GEMM 128x128, explicit 2-deep LDS pipeline (raw s_barrier +
// hand vmcnt(8); stage = 8 vmem/wave) — for N>=3072 GEMMs ----------------
#define TM 128
#define TN 128
#define BK 64

template<int EPI>
__global__ __launch_bounds__(256) void gemm_bt(
        const unsigned short* __restrict__ A, const unsigned short* __restrict__ Bw,
        const float* __restrict__ bias, const float* __restrict__ resid,
        float* __restrict__ Cf, unsigned short* __restrict__ Cb,
        int M, int N, int K) {
    __shared__ unsigned short sA[2][TM * BK];
    __shared__ unsigned short sB[2][TN * BK];
    int tid = threadIdx.x;
    int wave = tid >> 6, lane = tid & 63;
    int m_idx, n_idx;
    xcd_remap(m_idx, n_idx);
    int n0 = n_idx * TN, m0 = m_idx * TM;
    int wm = (wave & 1) * 64, wn = (wave >> 1) * 64;
    int l15 = lane & 15, quad = lane >> 4;

    int srow = wave * 32 + (lane >> 3);
    int scg  = (lane & 7) ^ (srow & 7);
    const unsigned short* Ag = A  + (size_t)(m0 + srow) * K + scg * 8;
    const unsigned short* Bg = Bw + (size_t)(n0 + srow) * K + scg * 8;

    floatx4 acc[4][4];
#pragma unroll
    for (int i = 0; i < 4; ++i)
#pragma unroll
        for (int j = 0; j < 4; ++j) acc[i][j] = (floatx4)0.f;

    auto stage = [&](int kt, int bsel) {
        int k0 = kt * BK;
#pragma unroll
        for (int p = 0; p < 4; ++p) {
            __builtin_amdgcn_global_load_lds((gas_ptr)(Ag + k0 + p * 8 * K),
                (las_ptr)&sA[bsel][(wave * 32 + p * 8) * BK], 16, 0, 0);
            __builtin_amdgcn_global_load_lds((gas_ptr)(Bg + k0 + p * 8 * K),
                (las_ptr)&sB[bsel][(wave * 32 + p * 8) * BK], 16, 0, 0);
        }
    };

    int T = K / BK;
    stage(0, 0);
    stage(1, 1);
    for (int i = 0; i < T; ++i) {
        if (i + 1 < T) { asm volatile("s_waitcnt vmcnt(8)" ::: "memory"); }
        else           { asm volatile("s_waitcnt vmcnt(0)" ::: "memory"); }
        __builtin_amdgcn_s_barrier();
        int bs = i & 1;
#pragma unroll
        for (int kk8 = 0; kk8 < 8; kk8 += 4) {
            shortx8 af[4], bfr[4];
#pragma unroll
            for (int ii = 0; ii < 4; ++ii) {
                int R = wm + ii * 16 + l15;
                int sc = (quad + kk8) ^ (R & 7);
                af[ii] = *(const shortx8*)&sA[bs][(R * 8 + sc) * 8];
            }
#pragma unroll
            for (int j = 0; j < 4; ++j) {
                int R = wn + j * 16 + l15;
                int sc = (quad + kk8) ^ (R & 7);
                bfr[j] = *(const shortx8*)&sB[bs][(R * 8 + sc) * 8];
            }
#pragma unroll
            for (int ii = 0; ii < 4; ++ii)
#pragma unroll
                for (int j = 0; j < 4; ++j)
                    acc[ii][j] = __builtin_amdgcn_mfma_f32_16x16x32_bf16(af[ii], bfr[j], acc[ii][j], 0, 0, 0);
        }
        __builtin_amdgcn_s_barrier();
        if (i + 2 < T) stage(i + 2, bs);
    }

#pragma unroll
    for (int i = 0; i < 4; ++i) {
        int row = m0 + wm + i * 16 + quad * 4;
#pragma unroll
        for (int j = 0; j < 4; ++j) {
            int col = n0 + wn + j * 16 + l15;
            float bs = bias[col];
#pragma unroll
            for (int r = 0; r < 4; ++r) {
                float v = acc[i][j][r] + bs;
                int rr = row + r;
                if (EPI & 1) v = gelu_fast(v);
                if (EPI & 2) v += resid[(size_t)rr * N + col];
                if (EPI & 4) Cf[(size_t)rr * N + col] = v;
                if (EPI & 8) Cb[(size_t)rr * N + col] = f2bf(v);
            }
        }
    }
}

// ---------------- GEMM 128x64, explicit 2-deep LDS pipeline — N=1024 GEMMs ----------------
template<int EPI>
__global__ __launch_bounds__(256) void gemm_n64(
        const unsigned short* __restrict__ A, const unsigned short* __restrict__ Bw,
        const float* __restrict__ bias, const float* __restrict__ resid,
        float* __restrict__ Cf, unsigned short* __restrict__ Cb,
        int M, int N, int K) {
    __shared__ unsigned short sA[2][TM * BK];
    __shared__ unsigned short sB[2][64 * BK];
    int tid = threadIdx.x;
    int wave = tid >> 6, lane = tid & 63;
    int m_idx, n_idx;
    xcd_remap(m_idx, n_idx);
    int n0 = n_idx * 64, m0 = m_idx * TM;
    int wm = (wave & 1) * 64, wn = (wave >> 1) * 32;
    int l15 = lane & 15, quad = lane >> 4;

    int srow = wave * 32 + (lane >> 3);
    int scg  = (lane & 7) ^ (srow & 7);
    const unsigned short* Ag = A + (size_t)(m0 + srow) * K + scg * 8;
    int srB  = wave * 16 + (lane >> 3);
    int scgB = (lane & 7) ^ (srB & 7);
    const unsigned short* Bg = Bw + (size_t)(n0 + srB) * K + scgB * 8;

    floatx4 acc[4][2];
#pragma unroll
    for (int i = 0; i < 4; ++i)
#pragma unroll
        for (int j = 0; j < 2; ++j) acc[i][j] = (floatx4)0.f;

    auto stage = [&](int kt, int bsel) {
        int k0 = kt * BK;
#pragma unroll
        for (int p = 0; p < 4; ++p)
            __builtin_amdgcn_global_load_lds((gas_ptr)(Ag + k0 + p * 8 * K),
                (las_ptr)&sA[bsel][(wave * 32 + p * 8) * BK], 16, 0, 0);
#pragma unroll
        for (int p = 0; p < 2; ++p)
            __builtin_amdgcn_global_load_lds((gas_ptr)(Bg + k0 + p * 8 * K),
                (las_ptr)&sB[bsel][(wave * 16 + p * 8) * BK], 16, 0, 0);
    };

    int T = K / BK;
    stage(0, 0);
    stage(1, 1);
    for (int i = 0; i < T; ++i) {
        if (i + 1 < T) { asm volatile("s_waitcnt vmcnt(6)" ::: "memory"); }
        else           { asm volatile("s_waitcnt vmcnt(0)" ::: "memory"); }
        __builtin_amdgcn_s_barrier();
        int bs = i & 1;
#pragma unroll
        for (int kk8 = 0; kk8 < 8; kk8 += 4) {
            shortx8 af[4], bfr[2];
#pragma unroll
            for (int ii = 0; ii < 4; ++ii) {
                int R = wm + ii * 16 + l15;
                int sc = (quad + kk8) ^ (R & 7);
                af[ii] = *(const shortx8*)&sA[bs][(R * 8 + sc) * 8];
            }
#pragma unroll
            for (int j = 0; j < 2; ++j) {
                int R = wn + j * 16 + l15;
                int sc = (quad + kk8) ^ (R & 7);
                bfr[j] = *(const shortx8*)&sB[bs][(R * 8 + sc) * 8];
            }
#pragma unroll
            for (int ii = 0; ii < 4; ++ii)
#pragma unroll
                for (int j = 0; j < 2; ++j)
                    acc[ii][j] = __builtin_amdgcn_mfma_f32_16x16x32_bf16(af[ii], bfr[j], acc[ii][j], 0, 0, 0);
        }
        __builtin_amdgcn_s_barrier();
        if (i + 2 < T) stage(i + 2, bs);
    }

#pragma unroll
    for (int i = 0; i < 4; ++i) {
        int row = m0 + wm + i * 16 + quad * 4;
#pragma unroll
        for (int j = 0; j < 2; ++j) {
            int col = n0 + wn + j * 16 + l15;
            float bs = bias[col];
#pragma unroll
            for (int r = 0; r < 4; ++r) {
                float v = acc[i][j][r] + bs;
                int rr = row + r;
                if (EPI & 1) v = gelu_fast(v);
                if (EPI & 2) v += resid[(size_t)rr * N + col];
                if (EPI & 4) Cf[(size_t)rr * N + col] = v;
                if (EPI & 8) Cb[(size_t)rr * N + col] = f2bf(v);
            }
        }
    }
}

// ---------------- V transpose: qkv[.,2048+h*64+d] -> vT[bh][d][t] ----------------
__global__ __launch_bounds__(256) void vtrans_kernel(const unsigned short* __restrict__ qkv,
                                                     unsigned short* __restrict__ vT) {
    __shared__ unsigned short tile[64 * 72];
    int tid = threadIdx.x;
    int bh = blockIdx.y, b = bh >> 4, h = bh & 15;
    int t0 = blockIdx.x * 64;
    const unsigned short* vsrc = qkv + (size_t)b * SEQ * QKV_N + 2 * E_DIM + h * HD;
#pragma unroll
    for (int p = 0; p < 2; ++p) {
        int idx = p * 256 + tid;
        int row = idx >> 3, col = (idx & 7) * 8;
        *(shortx8*)&tile[row * 72 + col] =
            *(const shortx8*)&vsrc[(size_t)(t0 + row) * QKV_N + col];
    }
    __syncthreads();
    int d = tid >> 2, tch = (tid & 3) * 16;
    unsigned short* dst = vT + (size_t)bh * HD * SEQ + (size_t)d * SEQ + t0 + tch;
    shortx8 a0, a1;
#pragma unroll
    for (int j = 0; j < 8; ++j) a0[j] = (short)tile[(tch + j) * 72 + d];
#pragma unroll
    for (int j = 0; j < 8; ++j) a1[j] = (short)tile[(tch + 8 + j) * 72 + d];
    *(shortx8*)&dst[0] = a0;
    *(shortx8*)&dst[8] = a1;
}

// ---------------- Flash attention: 64-key tiles, paired q-tiles, swizzled LDS ----------------
__global__ __launch_bounds__(256) void attn_kernel(
        const unsigned short* __restrict__ qkv, const unsigned short* __restrict__ vT,
        unsigned short* __restrict__ out) {
    __shared__ unsigned short kt[64 * 64];
    __shared__ unsigned short vt[64 * 64];
    __shared__ unsigned short ps[4][16 * 64];
    int tid = threadIdx.x;
    int wave = tid >> 6, lane = tid & 63, l15 = lane & 15, quad = lane >> 4;
    int bh = blockIdx.y, b = bh >> 4, h = bh & 15;
    const unsigned short* qbase = qkv + (size_t)b * SEQ * QKV_N + h * HD;
    const unsigned short* kbase = qbase + E_DIM;
    const unsigned short* vtb = vT + (size_t)bh * HD * SEQ;

    int srl = lane >> 3;
    int scg = (lane & 7) ^ srl;

    const float scale = 0.125f * 1.44269504f;

    for (int pass = 0; pass < 2; ++pass) {
        int qt = (pass == 0) ? blockIdx.x : (15 - blockIdx.x);
        int q0 = qt * 64;
        int qrow = q0 + wave * 16;

        shortx8 qa0 = *(const shortx8*)&qbase[(size_t)(qrow + l15) * QKV_N + quad * 8];
        shortx8 qa1 = *(const shortx8*)&qbase[(size_t)(qrow + l15) * QKV_N + 32 + quad * 8];

        floatx4 o[4];
        for (int d = 0; d < 4; ++d) o[d] = (floatx4)0.f;
        float mrun[4], lrun[4];
        for (int r = 0; r < 4; ++r) { mrun[r] = -1e30f; lrun[r] = 0.f; }

        int ntile = qt + 1;
        for (int t = 0; t < ntile; ++t) {
            int s0 = t * 64;
            __syncthreads();
#pragma unroll
            for (int p = 0; p < 2; ++p) {
                int rbase = p * 32 + wave * 8;
                __builtin_amdgcn_global_load_lds(
                    (gas_ptr)&kbase[(size_t)(s0 + rbase + srl) * QKV_N + scg * 8],
                    (las_ptr)&kt[rbase * 64], 16, 0, 0);
                __builtin_amdgcn_global_load_lds(
                    (gas_ptr)&vtb[(size_t)(rbase + srl) * SEQ + s0 + scg * 8],
                    (las_ptr)&vt[rbase * 64], 16, 0, 0);
            }
            __syncthreads();

            floatx4 sfr[4];
#pragma unroll
            for (int ct = 0; ct < 4; ++ct) {
                int R = ct * 16 + l15;
                int sc0 = quad ^ (R & 7), sc1 = (4 + quad) ^ (R & 7);
                shortx8 kb0 = *(const shortx8*)&kt[(R * 8 + sc0) * 8];
                shortx8 kb1 = *(const shortx8*)&kt[(R * 8 + sc1) * 8];
                floatx4 s4 = (floatx4)0.f;
                s4 = __builtin_amdgcn_mfma_f32_16x16x32_bf16(qa0, kb0, s4, 0, 0, 0);
                s4 = __builtin_amdgcn_mfma_f32_16x16x32_bf16(qa1, kb1, s4, 0, 0, 0);
                sfr[ct] = s4;
            }

            bool masked = (t == ntile - 1);
#pragma unroll
            for (int r = 0; r < 4; ++r) {
                int qg = qrow + quad * 4 + r;
                float sv[4];
                float mx = mrun[r];
#pragma unroll
                for (int ct = 0; ct < 4; ++ct) {
                    float v = sfr[ct][r] * scale;
                    if (masked && (s0 + ct * 16 + l15 > qg)) v = -1e30f;
                    sv[ct] = v;
                    mx = fmaxf(mx, v);
                }
                for (int mm = 8; mm; mm >>= 1) mx = fmaxf(mx, __shfl_xor(mx, mm));
                float alpha = exp2f(mrun[r] - mx);
                mrun[r] = mx;
                float sum = 0.f;
                float pv[4];
#pragma unroll
                for (int ct = 0; ct < 4; ++ct) { pv[ct] = exp2f(sv[ct] - mx); sum += pv[ct]; }
                for (int mm = 8; mm; mm >>= 1) sum += __shfl_xor(sum, mm);
                lrun[r] = lrun[r] * alpha + sum;
#pragma unroll
                for (int d = 0; d < 4; ++d) o[d][r] *= alpha;
                int row = quad * 4 + r;
#pragma unroll
                for (int ct = 0; ct < 4; ++ct) {
                    int g = ct * 2 + (l15 >> 3);
                    int sc = g ^ (row & 7);
                    ps[wave][row * 64 + sc * 8 + (l15 & 7)] = f2bf(pv[ct]);
                }
            }
            shortx8 pa0, pa1;
            {
                int sc0 = quad ^ (l15 & 7), sc1 = (4 + quad) ^ (l15 & 7);
                pa0 = *(const shortx8*)&ps[wave][(l15 * 8 + sc0) * 8];
                pa1 = *(const shortx8*)&ps[wave][(l15 * 8 + sc1) * 8];
            }
#pragma unroll
            for (int d = 0; d < 4; ++d) {
                int R = d * 16 + l15;
                int sc0 = quad ^ (R & 7), sc1 = (4 + quad) ^ (R & 7);
                shortx8 vb0 = *(const shortx8*)&vt[(R * 8 + sc0) * 8];
                shortx8 vb1 = *(const shortx8*)&vt[(R * 8 + sc1) * 8];
                o[d] = __builtin_amdgcn_mfma_f32_16x16x32_bf16(pa0, vb0, o[d], 0, 0, 0);
                o[d] = __builtin_amdgcn_mfma_f32_16x16x32_bf16(pa1, vb1, o[d], 0, 0, 0);
            }
        }

#pragma unroll
        for (int r = 0; r < 4; ++r) {
            float inv = 1.0f / lrun[r];
            int m = (b << 10) + qrow + quad * 4 + r;
#pragma unroll
            for (int d = 0; d < 4; ++d)
                out[(size_t)m * E_DIM + h * HD + d * 16 + l15] = f2bf(o[d][r] * inv);
        }
    }
}

// ---------------- launch ----------------
extern "C" void kernel_launch(void* const* d_in, const int* in_sizes, int n_in,
                              void* d_out, int out_size, void* d_ws, size_t ws_size,
                              hipStream_t stream) {
    const float* x     = (const float*)d_in[0];
    const float* ln1_w = (const float*)d_in[1];
    const float* ln1_b = (const float*)d_in[2];
    const float* ln2_w = (const float*)d_in[3];
    const float* ln2_b = (const float*)d_in[4];
    const float* qkv_w = (const float*)d_in[5];
    const float* qkv_b = (const float*)d_in[6];
    const float* out_w = (const float*)d_in[7];
    const float* out_b = (const float*)d_in[8];
    const float* fc1_w = (const float*)d_in[9];
    const float* fc1_b = (const float*)d_in[10];
    const float* fc2_w = (const float*)d_in[11];
    const float* fc2_b = (const float*)d_in[12];

    char* ws = (char*)d_ws;
    size_t off = 0;
    auto alloc = [&](size_t bytes) { char* p = ws + off; off += bytes; return p; };
    unsigned short* wq   = (unsigned short*)alloc((size_t)3 * E_DIM * E_DIM * 2);
    unsigned short* wo   = (unsigned short*)alloc((size_t)E_DIM * E_DIM * 2);
    unsigned short* w1   = (unsigned short*)alloc((size_t)F_DIM * E_DIM * 2);
    unsigned short* w2   = (unsigned short*)alloc((size_t)E_DIM * F_DIM * 2);
    unsigned short* h1   = (unsigned short*)alloc((size_t)MROWS * E_DIM * 2);
    unsigned short* qkvb = (unsigned short*)alloc((size_t)MROWS * QKV_N * 2);
    unsigned short* vT   = (unsigned short*)alloc((size_t)BATCH * NH * HD * SEQ * 2);
    unsigned short* attn = (unsigned short*)alloc((size_t)MROWS * E_DIM * 2);
    float*          x1   = (float*)alloc((size_t)MROWS * E_DIM * 4);
    unsigned short* h2   = (unsigned short*)alloc((size_t)MROWS * E_DIM * 2);
    unsigned short* g    = (unsigned short*)alloc((size_t)MROWS * F_DIM * 2);

    {
        int n;
        n = 3 * E_DIM * E_DIM; f2b_kernel<<<(n + 255) / 256, 256, 0, stream>>>(qkv_w, wq, n);
        n = E_DIM * E_DIM;     f2b_kernel<<<(n + 255) / 256, 256, 0, stream>>>(out_w, wo, n);
        n = F_DIM * E_DIM;     f2b_kernel<<<(n + 255) / 256, 256, 0, stream>>>(fc1_w, w1, n);
        n = E_DIM * F_DIM;     f2b_kernel<<<(n + 255) / 256, 256, 0, stream>>>(fc2_w, w2, n);
    }

    ln_kernel<<<MROWS, 256, 0, stream>>>(x, ln1_w, ln1_b, h1);
    gemm_bt<8><<<dim3(QKV_N / TN, MROWS / TM), 256, 0, stream>>>(
        h1, wq, qkv_b, nullptr, nullptr, qkvb, MROWS, QKV_N, E_DIM);
    vtrans_kernel<<<dim3(SEQ / 64, BATCH * NH), 256, 0, stream>>>(qkvb, vT);
    attn_kernel<<<dim3(8, BATCH * NH), 256, 0, stream>>>(qkvb, vT, attn);
    // out proj + residual(x) -> x1 fp32   (N=1024: 128x64 tiles, 512 blocks)
    gemm_n64<2 | 4><<<dim3(E_DIM / 64, MROWS / TM), 256, 0, stream>>>(
        attn, wo, out_b, x, x1, nullptr, MROWS, E_DIM, E_DIM);
    ln_kernel<<<MROWS, 256, 0, stream>>>(x1, ln2_w, ln2_b, h2);
    gemm_bt<1 | 8><<<dim3(F_DIM / TN, MROWS / TM), 256, 0, stream>>>(
        h2, w1, fc1_b, nullptr, nullptr, g, MROWS, F_DIM, E_DIM);
    // FC2 + residual(x1) -> d_out fp32   (N=1024: 128x64 tiles, 512 blocks)
    gemm_n64<2 | 4><<<dim3(E_DIM / 64, MROWS / TM), 256, 0, stream>>>(
        g, w2, fc2_b, x1, (float*)d_out, nullptr, MROWS, E_DIM, F_DIM);
}

// Round 10
// 330.262 us; speedup vs baseline: 1.1577x; 1.0629x over previous
//
#include <hip/hip_runtime.h>

typedef float floatx4 __attribute__((ext_vector_type(4)));
typedef short shortx8 __attribute__((ext_vector_type(8)));

#define E_DIM 1024
#define F_DIM 4096
#define BATCH 4
#define SEQ 1024
#define NH 16
#define HD 64
#define MROWS (BATCH*SEQ)   // 4096
#define QKV_N (3*E_DIM)     // 3072

typedef const __attribute__((address_space(1))) unsigned int* gas_ptr;
typedef __attribute__((address_space(3))) unsigned int* las_ptr;

__device__ __forceinline__ unsigned short f2bf(float f) {
    union { float f; unsigned u; } un; un.f = f;
    unsigned u = un.u;
    u += 0x7fffu + ((u >> 16) & 1u);   // RNE
    return (unsigned short)(u >> 16);
}

// tanh-form GELU, division via v_rcp_f32 (1 inst, ~1 ulp)
__device__ __forceinline__ float gelu_fast(float v) {
    float u = 0.7978845608f * (v + 0.044715f * v * v * v);
    float t = __builtin_exp2f(-2.885390082f * u);   // 2*log2(e)*u
    return v * __builtin_amdgcn_rcpf(1.0f + t);
}

// XCD-aware tile remap, m-fastest within XCD (see R6/R7 notes).
__device__ __forceinline__ void xcd_remap(int& m_idx, int& n_idx) {
    int nt = gridDim.x;
    int mt_x = gridDim.y >> 3;
    int lin = blockIdx.y * nt + blockIdx.x;
    int xcd = lin & 7, loc = lin >> 3;
    int n = loc / mt_x;
    int m_local = loc - n * mt_x;
    m_idx = xcd * mt_x + m_local;
    n_idx = n;
}

// ---------------- fused fp32 -> bf16 convert of all 4 weight tensors ----------------
#define S_QKV (3*E_DIM*E_DIM)          // 3145728
#define S_WO  (E_DIM*E_DIM)            // 1048576
#define S_W1  (F_DIM*E_DIM)            // 4194304
#define S_TOT (S_QKV + S_WO + 2*S_W1)  // 12582912
__global__ __launch_bounds__(256) void f2b_all(
        const float* __restrict__ qkv_w, const float* __restrict__ out_w,
        const float* __restrict__ fc1_w, const float* __restrict__ fc2_w,
        unsigned short* __restrict__ wq, unsigned short* __restrict__ wo,
        unsigned short* __restrict__ w1, unsigned short* __restrict__ w2) {
    long idx = ((long)blockIdx.x * 256 + threadIdx.x) * 4;
    const float* src; unsigned short* dst; long off;
    if (idx < S_QKV)                    { src = qkv_w; dst = wq; off = idx; }
    else if (idx < S_QKV + S_WO)        { src = out_w; dst = wo; off = idx - S_QKV; }
    else if (idx < S_QKV + S_WO + S_W1) { src = fc1_w; dst = w1; off = idx - S_QKV - S_WO; }
    else                                { src = fc2_w; dst = w2; off = idx - S_QKV - S_WO - S_W1; }
    float4 v = *(const float4*)&src[off];
    ushort4 o;
    o.x = f2bf(v.x); o.y = f2bf(v.y); o.z = f2bf(v.z); o.w = f2bf(v.w);
    *(ushort4*)&dst[off] = o;
}

// ---------------- LayerNorm (row=1024), fp32 in, bf16 out ----------------
__global__ __launch_bounds__(256) void ln_kernel(const float* __restrict__ x,
                                                 const float* __restrict__ w,
                                                 const float* __restrict__ b,
                                                 unsigned short* __restrict__ out) {
    int row = blockIdx.x;
    const float* xr = x + (size_t)row * E_DIM;
    float v[4];
    float s = 0.f, ss = 0.f;
    for (int i = 0; i < 4; ++i) {
        v[i] = xr[threadIdx.x + i * 256];
        s += v[i]; ss += v[i] * v[i];
    }
    for (int m = 32; m; m >>= 1) { s += __shfl_xor(s, m); ss += __shfl_xor(ss, m); }
    __shared__ float red[8];
    int wave = threadIdx.x >> 6;
    if ((threadIdx.x & 63) == 0) { red[wave] = s; red[wave + 4] = ss; }
    __syncthreads();
    s = red[0] + red[1] + red[2] + red[3];
    ss = red[4] + red[5] + red[6] + red[7];
    float mu = s * (1.0f / E_DIM);
    float var = ss * (1.0f / E_DIM) - mu * mu;
    float rs = rsqrtf(var + 1e-5f);
    for (int i = 0; i < 4; ++i) {
        int c = threadIdx.x + i * 256;
        out[(size_t)row * E_DIM + c] = f2bf((v[i] - mu) * rs * w[c] + b[c]);
    }
}

// ---------------- GEMM 128x128, 2-deep LDS pipeline (raw s_barrier + vmcnt(8)) ----------------
#define TM 128
#define TN 128
#define BK 64

template<int EPI>
__global__ __launch_bounds__(256) void gemm_bt(
        const unsigned short* __restrict__ A, const unsigned short* __restrict__ Bw,
        const float* __restrict__ bias, const float* __restrict__ resid,
        float* __restrict__ Cf, unsigned short* __restrict__ Cb,
        int M, int N, int K) {
    __shared__ unsigned short sA[2][TM * BK];
    __shared__ unsigned short sB[2][TN * BK];
    int tid = threadIdx.x;
    int wave = tid >> 6, lane = tid & 63;
    int m_idx, n_idx;
    xcd_remap(m_idx, n_idx);
    int n0 = n_idx * TN, m0 = m_idx * TM;
    int wm = (wave & 1) * 64, wn = (wave >> 1) * 64;
    int l15 = lane & 15, quad = lane >> 4;

    int srow = wave * 32 + (lane >> 3);
    int scg  = (lane & 7) ^ (srow & 7);
    const unsigned short* Ag = A  + (size_t)(m0 + srow) * K + scg * 8;
    const unsigned short* Bg = Bw + (size_t)(n0 + srow) * K + scg * 8;

    floatx4 acc[4][4];
#pragma unroll
    for (int i = 0; i < 4; ++i)
#pragma unroll
        for (int j = 0; j < 4; ++j) acc[i][j] = (floatx4)0.f;

    auto stage = [&](int kt, int bsel) {
        int k0 = kt * BK;
#pragma unroll
        for (int p = 0; p < 4; ++p) {
            __builtin_amdgcn_global_load_lds((gas_ptr)(Ag + k0 + p * 8 * K),
                (las_ptr)&sA[bsel][(wave * 32 + p * 8) * BK], 16, 0, 0);
            __builtin_amdgcn_global_load_lds((gas_ptr)(Bg + k0 + p * 8 * K),
                (las_ptr)&sB[bsel][(wave * 32 + p * 8) * BK], 16, 0, 0);
        }
    };

    int T = K / BK;
    stage(0, 0);
    stage(1, 1);
    for (int i = 0; i < T; ++i) {
        if (i + 1 < T) { asm volatile("s_waitcnt vmcnt(8)" ::: "memory"); }
        else           { asm volatile("s_waitcnt vmcnt(0)" ::: "memory"); }
        __builtin_amdgcn_s_barrier();
        int bs = i & 1;
#pragma unroll
        for (int kk8 = 0; kk8 < 8; kk8 += 4) {
            shortx8 af[4], bfr[4];
#pragma unroll
            for (int ii = 0; ii < 4; ++ii) {
                int R = wm + ii * 16 + l15;
                int sc = (quad + kk8) ^ (R & 7);
                af[ii] = *(const shortx8*)&sA[bs][(R * 8 + sc) * 8];
            }
#pragma unroll
            for (int j = 0; j < 4; ++j) {
                int R = wn + j * 16 + l15;
                int sc = (quad + kk8) ^ (R & 7);
                bfr[j] = *(const shortx8*)&sB[bs][(R * 8 + sc) * 8];
            }
#pragma unroll
            for (int ii = 0; ii < 4; ++ii)
#pragma unroll
                for (int j = 0; j < 4; ++j)
                    acc[ii][j] = __builtin_amdgcn_mfma_f32_16x16x32_bf16(af[ii], bfr[j], acc[ii][j], 0, 0, 0);
        }
        __builtin_amdgcn_s_barrier();
        if (i + 2 < T) stage(i + 2, bs);
    }

#pragma unroll
    for (int i = 0; i < 4; ++i) {
        int row = m0 + wm + i * 16 + quad * 4;
#pragma unroll
        for (int j = 0; j < 4; ++j) {
            int col = n0 + wn + j * 16 + l15;
            float bs = bias[col];
#pragma unroll
            for (int r = 0; r < 4; ++r) {
                float v = acc[i][j][r] + bs;
                int rr = row + r;
                if (EPI & 1) v = gelu_fast(v);
                if (EPI & 2) v += resid[(size_t)rr * N + col];
                if (EPI & 4) Cf[(size_t)rr * N + col] = v;
                if (EPI & 8) Cb[(size_t)rr * N + col] = f2bf(v);
            }
        }
    }
}

// ---------------- GEMM 128x64, 3-deep LDS pipeline (prefetch distance 2,
// consume-wait vmcnt(12): tiles i+1,i+2 = 12 loads stay in flight) ----------------
template<int EPI>
__global__ __launch_bounds__(256) void gemm_n64(
        const unsigned short* __restrict__ A, const unsigned short* __restrict__ Bw,
        const float* __restrict__ bias, const float* __restrict__ resid,
        float* __restrict__ Cf, unsigned short* __restrict__ Cb,
        int M, int N, int K) {
    __shared__ unsigned short sA[3][TM * BK];
    __shared__ unsigned short sB[3][64 * BK];
    int tid = threadIdx.x;
    int wave = tid >> 6, lane = tid & 63;
    int m_idx, n_idx;
    xcd_remap(m_idx, n_idx);
    int n0 = n_idx * 64, m0 = m_idx * TM;
    int wm = (wave & 1) * 64, wn = (wave >> 1) * 32;
    int l15 = lane & 15, quad = lane >> 4;

    int srow = wave * 32 + (lane >> 3);
    int scg  = (lane & 7) ^ (srow & 7);
    const unsigned short* Ag = A + (size_t)(m0 + srow) * K + scg * 8;
    int srB  = wave * 16 + (lane >> 3);
    int scgB = (lane & 7) ^ (srB & 7);
    const unsigned short* Bg = Bw + (size_t)(n0 + srB) * K + scgB * 8;

    floatx4 acc[4][2];
#pragma unroll
    for (int i = 0; i < 4; ++i)
#pragma unroll
        for (int j = 0; j < 2; ++j) acc[i][j] = (floatx4)0.f;

    auto stage = [&](int kt, int bsel) {
        int k0 = kt * BK;
#pragma unroll
        for (int p = 0; p < 4; ++p)
            __builtin_amdgcn_global_load_lds((gas_ptr)(Ag + k0 + p * 8 * K),
                (las_ptr)&sA[bsel][(wave * 32 + p * 8) * BK], 16, 0, 0);
#pragma unroll
        for (int p = 0; p < 2; ++p)
            __builtin_amdgcn_global_load_lds((gas_ptr)(Bg + k0 + p * 8 * K),
                (las_ptr)&sB[bsel][(wave * 16 + p * 8) * BK], 16, 0, 0);
    };

    int T = K / BK;   // 16 (out-proj) or 64 (FC2)
    stage(0, 0);
    stage(1, 1);
    stage(2, 2);
    int bs = 0;
    for (int i = 0; i < T; ++i) {
        if (i + 2 < T)      { asm volatile("s_waitcnt vmcnt(12)" ::: "memory"); }
        else if (i + 1 < T) { asm volatile("s_waitcnt vmcnt(6)"  ::: "memory"); }
        else                { asm volatile("s_waitcnt vmcnt(0)"  ::: "memory"); }
        __builtin_amdgcn_s_barrier();
#pragma unroll
        for (int kk8 = 0; kk8 < 8; kk8 += 4) {
            shortx8 af[4], bfr[2];
#pragma unroll
            for (int ii = 0; ii < 4; ++ii) {
                int R = wm + ii * 16 + l15;
                int sc = (quad + kk8) ^ (R & 7);
                af[ii] = *(const shortx8*)&sA[bs][(R * 8 + sc) * 8];
            }
#pragma unroll
            for (int j = 0; j < 2; ++j) {
                int R = wn + j * 16 + l15;
                int sc = (quad + kk8) ^ (R & 7);
                bfr[j] = *(const shortx8*)&sB[bs][(R * 8 + sc) * 8];
            }
#pragma unroll
            for (int ii = 0; ii < 4; ++ii)
#pragma unroll
                for (int j = 0; j < 2; ++j)
                    acc[ii][j] = __builtin_amdgcn_mfma_f32_16x16x32_bf16(af[ii], bfr[j], acc[ii][j], 0, 0, 0);
        }
        __builtin_amdgcn_s_barrier();
        if (i + 3 < T) stage(i + 3, bs);
        bs = (bs == 2) ? 0 : bs + 1;
    }

#pragma unroll
    for (int i = 0; i < 4; ++i) {
        int row = m0 + wm + i * 16 + quad * 4;
#pragma unroll
        for (int j = 0; j < 2; ++j) {
            int col = n0 + wn + j * 16 + l15;
            float bs2 = bias[col];
#pragma unroll
            for (int r = 0; r < 4; ++r) {
                float v = acc[i][j][r] + bs2;
                int rr = row + r;
                if (EPI & 1) v = gelu_fast(v);
                if (EPI & 2) v += resid[(size_t)rr * N + col];
                if (EPI & 4) Cf[(size_t)rr * N + col] = v;
                if (EPI & 8) Cb[(size_t)rr * N + col] = f2bf(v);
            }
        }
    }
}

// ---------------- V transpose: qkv[.,2048+h*64+d] -> vT[bh][d][t] ----------------
__global__ __launch_bounds__(256) void vtrans_kernel(const unsigned short* __restrict__ qkv,
                                                     unsigned short* __restrict__ vT) {
    __shared__ unsigned short tile[64 * 72];
    int tid = threadIdx.x;
    int bh = blockIdx.y, b = bh >> 4, h = bh & 15;
    int t0 = blockIdx.x * 64;
    const unsigned short* vsrc = qkv + (size_t)b * SEQ * QKV_N + 2 * E_DIM + h * HD;
#pragma unroll
    for (int p = 0; p < 2; ++p) {
        int idx = p * 256 + tid;
        int row = idx >> 3, col = (idx & 7) * 8;
        *(shortx8*)&tile[row * 72 + col] =
            *(const shortx8*)&vsrc[(size_t)(t0 + row) * QKV_N + col];
    }
    __syncthreads();
    int d = tid >> 2, tch = (tid & 3) * 16;
    unsigned short* dst = vT + (size_t)bh * HD * SEQ + (size_t)d * SEQ + t0 + tch;
    shortx8 a0, a1;
#pragma unroll
    for (int j = 0; j < 8; ++j) a0[j] = (short)tile[(tch + j) * 72 + d];
#pragma unroll
    for (int j = 0; j < 8; ++j) a1[j] = (short)tile[(tch + 8 + j) * 72 + d];
    *(shortx8*)&dst[0] = a0;
    *(shortx8*)&dst[8] = a1;
}

// ---------------- Flash attention: 64-key tiles, paired q-tiles, swizzled LDS ----------------
__global__ __launch_bounds__(256) void attn_kernel(
        const unsigned short* __restrict__ qkv, const unsigned short* __restrict__ vT,
        unsigned short* __restrict__ out) {
    __shared__ unsigned short kt[64 * 64];
    __shared__ unsigned short vt[64 * 64];
    __shared__ unsigned short ps[4][16 * 64];
    int tid = threadIdx.x;
    int wave = tid >> 6, lane = tid & 63, l15 = lane & 15, quad = lane >> 4;
    int bh = blockIdx.y, b = bh >> 4, h = bh & 15;
    const unsigned short* qbase = qkv + (size_t)b * SEQ * QKV_N + h * HD;
    const unsigned short* kbase = qbase + E_DIM;
    const unsigned short* vtb = vT + (size_t)bh * HD * SEQ;

    int srl = lane >> 3;
    int scg = (lane & 7) ^ srl;

    const float scale = 0.125f * 1.44269504f;

    for (int pass = 0; pass < 2; ++pass) {
        int qt = (pass == 0) ? blockIdx.x : (15 - blockIdx.x);
        int q0 = qt * 64;
        int qrow = q0 + wave * 16;

        shortx8 qa0 = *(const shortx8*)&qbase[(size_t)(qrow + l15) * QKV_N + quad * 8];
        shortx8 qa1 = *(const shortx8*)&qbase[(size_t)(qrow + l15) * QKV_N + 32 + quad * 8];

        floatx4 o[4];
        for (int d = 0; d < 4; ++d) o[d] = (floatx4)0.f;
        float mrun[4], lrun[4];
        for (int r = 0; r < 4; ++r) { mrun[r] = -1e30f; lrun[r] = 0.f; }

        int ntile = qt + 1;
        for (int t = 0; t < ntile; ++t) {
            int s0 = t * 64;
            __syncthreads();
#pragma unroll
            for (int p = 0; p < 2; ++p) {
                int rbase = p * 32 + wave * 8;
                __builtin_amdgcn_global_load_lds(
                    (gas_ptr)&kbase[(size_t)(s0 + rbase + srl) * QKV_N + scg * 8],
                    (las_ptr)&kt[rbase * 64], 16, 0, 0);
                __builtin_amdgcn_global_load_lds(
                    (gas_ptr)&vtb[(size_t)(rbase + srl) * SEQ + s0 + scg * 8],
                    (las_ptr)&vt[rbase * 64], 16, 0, 0);
            }
            __syncthreads();

            floatx4 sfr[4];
#pragma unroll
            for (int ct = 0; ct < 4; ++ct) {
                int R = ct * 16 + l15;
                int sc0 = quad ^ (R & 7), sc1 = (4 + quad) ^ (R & 7);
                shortx8 kb0 = *(const shortx8*)&kt[(R * 8 + sc0) * 8];
                shortx8 kb1 = *(const shortx8*)&kt[(R * 8 + sc1) * 8];
                floatx4 s4 = (floatx4)0.f;
                s4 = __builtin_amdgcn_mfma_f32_16x16x32_bf16(qa0, kb0, s4, 0, 0, 0);
                s4 = __builtin_amdgcn_mfma_f32_16x16x32_bf16(qa1, kb1, s4, 0, 0, 0);
                sfr[ct] = s4;
            }

            bool masked = (t == ntile - 1);
#pragma unroll
            for (int r = 0; r < 4; ++r) {
                int qg = qrow + quad * 4 + r;
                float sv[4];
                float mx = mrun[r];
#pragma unroll
                for (int ct = 0; ct < 4; ++ct) {
                    float v = sfr[ct][r] * scale;
                    if (masked && (s0 + ct * 16 + l15 > qg)) v = -1e30f;
                    sv[ct] = v;
                    mx = fmaxf(mx, v);
                }
                for (int mm = 8; mm; mm >>= 1) mx = fmaxf(mx, __shfl_xor(mx, mm));
                float alpha = exp2f(mrun[r] - mx);
                mrun[r] = mx;
                float sum = 0.f;
                float pv[4];
#pragma unroll
                for (int ct = 0; ct < 4; ++ct) { pv[ct] = exp2f(sv[ct] - mx); sum += pv[ct]; }
                for (int mm = 8; mm; mm >>= 1) sum += __shfl_xor(sum, mm);
                lrun[r] = lrun[r] * alpha + sum;
#pragma unroll
                for (int d = 0; d < 4; ++d) o[d][r] *= alpha;
                int row = quad * 4 + r;
#pragma unroll
                for (int ct = 0; ct < 4; ++ct) {
                    int g = ct * 2 + (l15 >> 3);
                    int sc = g ^ (row & 7);
                    ps[wave][row * 64 + sc * 8 + (l15 & 7)] = f2bf(pv[ct]);
                }
            }
            shortx8 pa0, pa1;
            {
                int sc0 = quad ^ (l15 & 7), sc1 = (4 + quad) ^ (l15 & 7);
                pa0 = *(const shortx8*)&ps[wave][(l15 * 8 + sc0) * 8];
                pa1 = *(const shortx8*)&ps[wave][(l15 * 8 + sc1) * 8];
            }
#pragma unroll
            for (int d = 0; d < 4; ++d) {
                int R = d * 16 + l15;
                int sc0 = quad ^ (R & 7), sc1 = (4 + quad) ^ (R & 7);
                shortx8 vb0 = *(const shortx8*)&vt[(R * 8 + sc0) * 8];
                shortx8 vb1 = *(const shortx8*)&vt[(R * 8 + sc1) * 8];
                o[d] = __builtin_amdgcn_mfma_f32_16x16x32_bf16(pa0, vb0, o[d], 0, 0, 0);
                o[d] = __builtin_amdgcn_mfma_f32_16x16x32_bf16(pa1, vb1, o[d], 0, 0, 0);
            }
        }

#pragma unroll
        for (int r = 0; r < 4; ++r) {
            float inv = 1.0f / lrun[r];
            int m = (b << 10) + qrow + quad * 4 + r;
#pragma unroll
            for (int d = 0; d < 4; ++d)
                out[(size_t)m * E_DIM + h * HD + d * 16 + l15] = f2bf(o[d][r] * inv);
        }
    }
}

// ---------------- launch ----------------
extern "C" void kernel_launch(void* const* d_in, const int* in_sizes, int n_in,
                              void* d_out, int out_size, void* d_ws, size_t ws_size,
                              hipStream_t stream) {
    const float* x     = (const float*)d_in[0];
    const float* ln1_w = (const float*)d_in[1];
    const float* ln1_b = (const float*)d_in[2];
    const float* ln2_w = (const float*)d_in[3];
    const float* ln2_b = (const float*)d_in[4];
    const float* qkv_w = (const float*)d_in[5];
    const float* qkv_b = (const float*)d_in[6];
    const float* out_w = (const float*)d_in[7];
    const float* out_b = (const float*)d_in[8];
    const float* fc1_w = (const float*)d_in[9];
    const float* fc1_b = (const float*)d_in[10];
    const float* fc2_w = (const float*)d_in[11];
    const float* fc2_b = (const float*)d_in[12];

    char* ws = (char*)d_ws;
    size_t off = 0;
    auto alloc = [&](size_t bytes) { char* p = ws + off; off += bytes; return p; };
    unsigned short* wq   = (unsigned short*)alloc((size_t)3 * E_DIM * E_DIM * 2);
    unsigned short* wo   = (unsigned short*)alloc((size_t)E_DIM * E_DIM * 2);
    unsigned short* w1   = (unsigned short*)alloc((size_t)F_DIM * E_DIM * 2);
    unsigned short* w2   = (unsigned short*)alloc((size_t)E_DIM * F_DIM * 2);
    unsigned short* h1   = (unsigned short*)alloc((size_t)MROWS * E_DIM * 2);
    unsigned short* qkvb = (unsigned short*)alloc((size_t)MROWS * QKV_N * 2);
    unsigned short* vT   = (unsigned short*)alloc((size_t)BATCH * NH * HD * SEQ * 2);
    unsigned short* attn = (unsigned short*)alloc((size_t)MROWS * E_DIM * 2);
    float*          x1   = (float*)alloc((size_t)MROWS * E_DIM * 4);
    unsigned short* h2   = (unsigned short*)alloc((size_t)MROWS * E_DIM * 2);
    unsigned short* g    = (unsigned short*)alloc((size_t)MROWS * F_DIM * 2);

    // fused weight conversion (12.58M elems, float4 -> ushort4)
    f2b_all<<<S_TOT / 4 / 256, 256, 0, stream>>>(qkv_w, out_w, fc1_w, fc2_w, wq, wo, w1, w2);

    ln_kernel<<<MROWS, 256, 0, stream>>>(x, ln1_w, ln1_b, h1);
    gemm_bt<8><<<dim3(QKV_N / TN, MROWS / TM), 256, 0, stream>>>(
        h1, wq, qkv_b, nullptr, nullptr, qkvb, MROWS, QKV_N, E_DIM);
    vtrans_kernel<<<dim3(SEQ / 64, BATCH * NH), 256, 0, stream>>>(qkvb, vT);
    attn_kernel<<<dim3(8, BATCH * NH), 256, 0, stream>>>(qkvb, vT, attn);
    // out proj + residual(x) -> x1 fp32   (N=1024: 128x64 tiles, 512 blocks)
    gemm_n64<2 | 4><<<dim3(E_DIM / 64, MROWS / TM), 256, 0, stream>>>(
        attn, wo, out_b, x, x1, nullptr, MROWS, E_DIM, E_DIM);
    ln_kernel<<<MROWS, 256, 0, stream>>>(x1, ln2_w, ln2_b, h2);
    gemm_bt<1 | 8><<<dim3(F_DIM / TN, MROWS / TM), 256, 0, stream>>>(
        h2, w1, fc1_b, nullptr, nullptr, g, MROWS, F_DIM, E_DIM);
    // FC2 + residual(x1) -> d_out fp32   (N=1024: 128x64 tiles, 512 blocks)
    gemm_n64<2 | 4><<<dim3(E_DIM / 64, MROWS / TM), 256, 0, stream>>>(
        g, w2, fc2_b, x1, (float*)d_out, nullptr, MROWS, E_DIM, F_DIM);
}